// Round 12
// baseline (240.815 us; speedup 1.0000x reference)
//
#include <hip/hip_runtime.h>

constexpr int NTYPES = 8;
constexpr int NREL   = 6;
constexpr int NSLOT  = 7;          // 6 relations + self
constexpr int D      = 256;
constexpr int DIN    = 512;
constexpr int LDH    = NSLOT * D;  // 1792

using short8 = __attribute__((ext_vector_type(8))) short;
using f32x4  = __attribute__((ext_vector_type(4))) float;

__device__ __forceinline__ ushort f2b(float f) {  // f32 -> bf16 RNE
  unsigned u = __float_as_uint(f);
  u += 0x7fffu + ((u >> 16) & 1u);
  return (ushort)(u >> 16);
}
__device__ __forceinline__ float b2f(unsigned bits16) {
  return __uint_as_float(bits16 << 16);
}

#define GLOAD_LDS16(g, l)                                              \
  __builtin_amdgcn_global_load_lds(                                    \
      (__attribute__((address_space(1))) void*)(g),                    \
      (__attribute__((address_space(3))) void*)(l), 16, 0, 0)

// ---------------- tiny zero (runtime fillBuffer is slow in-graph) ----------------
__global__ void k_zero(int* __restrict__ p, int n) {
  int i = blockIdx.x * blockDim.x + threadIdx.x;
  if (i < n) p[i] = 0;
}

// ---------------- mega prep: degree | type-hist | cvtX | cvtW | packWcat -------
// one launch; the two atomic partitions (degree, count) co-schedule with the
// streaming partitions, hiding their latency (round-11 budget: ~25us of prep
// atomics were serialized behind ~11us of streaming).
__global__ void k_prep_fused(const int* __restrict__ dst, int* __restrict__ deg,
                             const int* __restrict__ ntype, int* __restrict__ blockcnt,
                             const float* __restrict__ X, ushort* __restrict__ Xb,
                             const float* __restrict__ Wa, ushort* __restrict__ Wab,
                             const float* __restrict__ Wrel, const float* __restrict__ Wself,
                             ushort* __restrict__ Wcat,
                             int N, int E, int nbE, int nbN, int nx, int nw,
                             int n4x, int n4w) {
  __shared__ int cnt[NTYPES];
  const int b = blockIdx.x;
  const int tid = threadIdx.x;
  if (b < nbE) {                               // degree atomics (deg zeroed in L0)
    int e = b * 256 + tid;
    if (e < E) atomicAdd(&deg[dst[e]], 1);
  } else if (b < nbE + nbN) {                  // per-block type histogram (ballot)
    const int bb = b - nbE;
    int i = bb * 256 + tid;
    if (tid < NTYPES) cnt[tid] = 0;
    __syncthreads();
    int t = (i < N) ? ntype[i] : -1;
#pragma unroll
    for (int ty = 0; ty < NTYPES; ++ty) {
      unsigned long long m = __ballot(t == ty);
      if ((tid & 63) == 0 && m) atomicAdd(&cnt[ty], __popcll(m));
    }
    __syncthreads();
    if (tid < NTYPES) blockcnt[bb * NTYPES + tid] = cnt[tid];
  } else if (b < nbE + nbN + nx) {             // X -> bf16
    int i = (b - nbE - nbN) * 256 + tid;
    if (i < n4x) {
      float4 v = ((const float4*)X)[i];
      ushort4 o; o.x = f2b(v.x); o.y = f2b(v.y); o.z = f2b(v.z); o.w = f2b(v.w);
      ((ushort4*)Xb)[i] = o;
    }
  } else if (b < nbE + nbN + nx + nw) {        // adapt_W -> bf16
    int i = (b - nbE - nbN - nx) * 256 + tid;
    if (i < n4w) {
      float4 v = ((const float4*)Wa)[i];
      ushort4 o; o.x = f2b(v.x); o.y = f2b(v.y); o.z = f2b(v.z); o.w = f2b(v.w);
      ((ushort4*)Wab)[i] = o;
    }
  } else {                                     // pack Wcat (transposed, bf16)
    int local = b - nbE - nbN - nx - nw;       // 0 .. 2*7*256-1
    int l = local / (NSLOT * 256);
    int s = (local % (NSLOT * 256)) / 256;
    int o = (local % 256) * 256 + tid;         // over D*D
    int e = o >> 8, d = o & 255;
    float v = (s < NREL) ? Wrel[(((size_t)l * NREL + s) * D + d) * D + e]
                         : Wself[((size_t)l * D + d) * D + e];
    Wcat[(((size_t)l * NSLOT + s) * D + e) * D + d] = f2b(v);
  }
}

// ---------------- fused scans: block0 = type scan, block1 = full degree scan ---
// replaces the 3-launch scan_block/scan_bsum/scan_add chain with one 256-thread
// single-block scan (79-elem serial chunks + LDS Hillis-Steele), also emitting
// cursor and inv_deg in the same pass.
__global__ void k_scan_fused(const int* __restrict__ blockcnt, int* __restrict__ boffset,
                             int* __restrict__ cnt, int* __restrict__ offt, int nbN,
                             const int* __restrict__ deg, int* __restrict__ rowptr,
                             int* __restrict__ cursor, float* __restrict__ inv,
                             int N, int E) {
  if (blockIdx.x == 0) {
    __shared__ int tot[NTYPES];
    __shared__ int base[NTYPES];
    int t = threadIdx.x;
    if (t < NTYPES) {
      int s = 0;
      for (int b = 0; b < nbN; ++b) {
        boffset[b * NTYPES + t] = s;
        s += blockcnt[b * NTYPES + t];
      }
      tot[t] = s;
      cnt[t] = s;
    }
    __syncthreads();
    if (t == 0) {
      int s = 0;
      for (int ty = 0; ty < NTYPES; ++ty) { base[ty] = s; offt[ty] = s; s += tot[ty]; }
    }
    __syncthreads();
    if (t < NTYPES)
      for (int b = 0; b < nbN; ++b) boffset[b * NTYPES + t] += base[t];
  } else {
    __shared__ int ssum[256];
    const int t = threadIdx.x;
    const int C = (N + 255) / 256;
    const int begin = t * C, end = min(begin + C, N);
    int s = 0;
    for (int i = begin; i < end; ++i) s += deg[i];
    ssum[t] = s;
    __syncthreads();
    for (int o = 1; o < 256; o <<= 1) {
      int v = (t >= o) ? ssum[t - o] : 0;
      __syncthreads();
      ssum[t] += v;
      __syncthreads();
    }
    int run = (t > 0) ? ssum[t - 1] : 0;   // exclusive base
    for (int i = begin; i < end; ++i) {
      int d = deg[i];
      rowptr[i] = run;
      cursor[i] = run;
      inv[i] = 1.0f / fmaxf((float)d, 1.0f);
      run += d;
    }
    if (t == 0) rowptr[N] = E;
  }
}

// ---------------- fused: type scatter (perm) | edge counting-sort (epack) ------
__global__ void k_scatter_sort(const int* __restrict__ ntype, const int* __restrict__ boffset,
                               int* __restrict__ perm, int N, int nbN,
                               const int* __restrict__ src, const int* __restrict__ dst,
                               const int* __restrict__ et, int* __restrict__ cursor,
                               int* __restrict__ epack, int E) {
  __shared__ int cur[NTYPES];
  const int b = blockIdx.x;
  if (b < nbN) {
    int i = b * 256 + threadIdx.x;
    if (threadIdx.x < NTYPES) cur[threadIdx.x] = boffset[b * NTYPES + threadIdx.x];
    __syncthreads();
    int t = (i < N) ? ntype[i] : -1;
    int lane = threadIdx.x & 63;
#pragma unroll
    for (int ty = 0; ty < NTYPES; ++ty) {
      unsigned long long m = __ballot(t == ty);
      if (m) {
        int wbase = 0;
        if (lane == 0) wbase = atomicAdd(&cur[ty], __popcll(m));
        wbase = __shfl(wbase, 0);
        if (t == ty) {
          int rank = __popcll(m & ((1ull << lane) - 1ull));
          perm[wbase + rank] = i;
        }
      }
    }
  } else {
    int e = (b - nbN) * 256 + threadIdx.x;
    if (e < E) {
      int pos = atomicAdd(&cursor[dst[e]], 1);
      epack[pos] = (src[e] << 3) | et[e];
    }
  }
}

// ---------------- MFMA GEMM (1D swizzled grid, LDS-staged epilogue) -------------
// C[m][n] = sum_k A[m][k] * B[n][k]   (B stored row-per-output-col, k-contiguous)
// BMxBN tile, 4 waves (2x2), BK=32, bf16 in / f32 acc / bf16 out.
// 1D grid, n-tile fastest, bijective XCD swizzle (T1/m204).
// K-loop barriers are REAL __syncthreads() (IR fence + vmcnt/lgkmcnt drain +
// s_barrier); raw s_barrier is IntrNoMem and let STAGE hoist (rounds 6-7 bugs).
template <int BM, int BN, int NTN, int KDIM, bool ADAPT, int OCC>
__global__ __launch_bounds__(256, OCC)
void k_mfma_gemm(const ushort* __restrict__ A, const ushort* __restrict__ B,
                 const float* __restrict__ bias,
                 const int* __restrict__ perm, const int* __restrict__ cnt,
                 const int* __restrict__ off,
                 ushort* __restrict__ Cout, int N, int ldC) {
  // bijective XCD swizzle (works for any nwg)
  const int nwg = gridDim.x;
  const int qq = nwg >> 3, rr = nwg & 7;
  const int xcd = blockIdx.x & 7, idx = blockIdx.x >> 3;
  const int wgid = (xcd < rr ? xcd * (qq + 1) : rr * (qq + 1) + (xcd - rr) * qq) + idx;

  int mcnt = N, mtile, ntile;
  const int* permt = nullptr;
  const ushort* Bt = B;
  const float* biast = bias;
  if (ADAPT) {
    const int mt = nwg / (NTYPES * NTN);
    const int t = wgid / (mt * NTN);
    const int rem = wgid % (mt * NTN);
    mtile = rem / NTN;
    ntile = rem % NTN;
    mcnt = cnt[t];
    permt = perm + off[t];
    Bt = B + (size_t)t * D * KDIM;
    biast = bias + t * D;
  } else {
    mtile = wgid / NTN;
    ntile = wgid % NTN;
  }
  const int m0 = mtile * BM;
  if (m0 >= mcnt) return;
  const int n0 = ntile * BN;

  __shared__ ushort SM[2][2][BM * 32];   // [buf][A=0/B=1][row*32+k]
  static_assert(BM * BN <= 2 * 2 * BM * 32, "C tile must fit in staging LDS");

  const int tid  = threadIdx.x;
  const int lane = tid & 63;
  const int w    = tid >> 6;
  constexpr int FR = BM / 32;
  constexpr int FC = BN / 32;
  const int wr   = (w >> 1) * (BM / 2);
  const int wc   = (w & 1) * (BN / 2);

  // staging: (BM/16) x 1KB calls per matrix; wave w does calls {w, w+4, ...}.
  // XOR swizzle on GLOBAL source slot (LDS dest linear), undone at ds_read.
  constexpr int PW = BM / 16 / 4;
  const ushort* gA[PW];
  const ushort* gB[PW];
  int lo[PW];
#pragma unroll
  for (int u = 0; u < PW; ++u) {
    const int c  = w + u * 4;
    const int r  = c * 16 + (lane >> 2);
    const int sl = (lane & 3) ^ ((r >> 1) & 3);
    int ga;
    if (ADAPT) ga = permt[min(m0 + r, mcnt - 1)];
    else       ga = min(m0 + r, N - 1);
    gA[u] = A + (size_t)ga * KDIM + sl * 8;
    gB[u] = Bt + (size_t)(n0 + r) * KDIM + sl * 8;
    lo[u] = c * 512;
  }

  auto STAGE = [&](int k0, int buf) {
#pragma unroll
    for (int u = 0; u < PW; ++u) {
      GLOAD_LDS16(gA[u] + k0, &SM[buf][0][lo[u]]);
      GLOAD_LDS16(gB[u] + k0, &SM[buf][1][lo[u]]);
    }
  };

  f32x4 acc[FR][FC] = {};
  const int r15 = lane & 15;
  const int g   = lane >> 4;
  const int gsw = g ^ ((r15 >> 1) & 3);

  STAGE(0, 0);
  __syncthreads();

  constexpr int NT = KDIM / 32;
  int curb = 0;
#pragma unroll
  for (int kt = 0; kt < NT; ++kt) {
    if (kt + 1 < NT) STAGE((kt + 1) * 32, curb ^ 1);   // prefetch next tile

    short8 af[FR], bf[FC];
#pragma unroll
    for (int i = 0; i < FR; ++i)
      af[i] = *(const short8*)(&SM[curb][0][(wr + i * 16 + r15) * 32 + gsw * 8]);
#pragma unroll
    for (int j = 0; j < FC; ++j)
      bf[j] = *(const short8*)(&SM[curb][1][(wc + j * 16 + r15) * 32 + gsw * 8]);
#pragma unroll
    for (int i = 0; i < FR; ++i)
#pragma unroll
      for (int j = 0; j < FC; ++j)
        acc[i][j] = __builtin_amdgcn_mfma_f32_16x16x32_bf16(af[i], bf[j], acc[i][j], 0, 0, 0);

    __syncthreads();   // real fence+barrier: prefetch landed, reads joined
    curb ^= 1;
  }

  // ---- epilogue: C/D layout (m89): col = lane&15, row = (lane>>4)*4 + reg ----
  ushort* Ct = (ushort*)SM;
#pragma unroll
  for (int i = 0; i < FR; ++i) {
#pragma unroll
    for (int q4 = 0; q4 < 4; ++q4) {
      const int row = wr + i * 16 + (lane >> 4) * 4 + q4;
#pragma unroll
      for (int j = 0; j < FC; ++j) {
        const int col = wc + j * 16 + r15;
        float v = acc[i][j][q4];
        if (ADAPT) v = tanhf(v + biast[n0 + col]);
        Ct[row * BN + col] = f2b(v);
      }
    }
  }
  __syncthreads();
  constexpr int C8 = BN / 8;
  constexpr int UNITS = BM * C8;
#pragma unroll
  for (int u0 = 0; u0 < UNITS; u0 += 256) {
    const int u = u0 + tid;
    const int row = u / C8, c8 = u % C8;
    const int rl = m0 + row;
    if (rl < mcnt) {
      const int grow = ADAPT ? permt[rl] : rl;
      *(short8*)(Cout + (size_t)grow * ldC + n0 + c8 * 8) =
          *(const short8*)(Ct + row * BN + c8 * 8);
    }
  }
}

// ---------------- CSR gather-combine ----------------
// out[v] = relu( (sum_{e in in(v)} Hall[src_e][rel_e*256 + :]) * inv[v]
//                + Hall[v][6*256 + :] + bias )
// one wave per node, lane owns 4 channels; edge loop 8-wide unrolled so 8
// independent L2/L3 gathers are in flight per wave.
template <bool LAST>
__global__ void k_combine(const ushort* __restrict__ Hall, const int* __restrict__ rowptr,
                          const int* __restrict__ epack, const float* __restrict__ invd,
                          const float* __restrict__ bias, void* __restrict__ outp, int N) {
  int v = blockIdx.x * 4 + (threadIdx.x >> 6);
  if (v >= N) return;
  int lane = threadIdx.x & 63;
  int e0 = rowptr[v], e1 = rowptr[v + 1];
  const uint2 s = *(const uint2*)(Hall + (size_t)v * LDH + NREL * D + lane * 4);
  float iv = invd[v];
  const float4 b4 = *(const float4*)(bias + lane * 4);

  float a0 = 0.f, a1 = 0.f, a2 = 0.f, a3 = 0.f;
  int e = e0;
  for (; e + 8 <= e1; e += 8) {
    uint2 u[8];
#pragma unroll
    for (int k = 0; k < 8; ++k) {
      int p = epack[e + k];
      u[k] = *(const uint2*)(Hall + (size_t)(p >> 3) * LDH + (p & 7) * D + lane * 4);
    }
#pragma unroll
    for (int k = 0; k < 8; ++k) {
      a0 += b2f(u[k].x & 0xffffu);
      a1 += __uint_as_float(u[k].x & 0xffff0000u);
      a2 += b2f(u[k].y & 0xffffu);
      a3 += __uint_as_float(u[k].y & 0xffff0000u);
    }
  }
  if (e + 4 <= e1) {
    uint2 u[4];
#pragma unroll
    for (int k = 0; k < 4; ++k) {
      int p = epack[e + k];
      u[k] = *(const uint2*)(Hall + (size_t)(p >> 3) * LDH + (p & 7) * D + lane * 4);
    }
#pragma unroll
    for (int k = 0; k < 4; ++k) {
      a0 += b2f(u[k].x & 0xffffu);
      a1 += __uint_as_float(u[k].x & 0xffff0000u);
      a2 += b2f(u[k].y & 0xffffu);
      a3 += __uint_as_float(u[k].y & 0xffff0000u);
    }
    e += 4;
  }
  for (; e < e1; ++e) {
    int p = epack[e];
    const uint2 u = *(const uint2*)(Hall + (size_t)(p >> 3) * LDH + (p & 7) * D + lane * 4);
    a0 += b2f(u.x & 0xffffu);
    a1 += __uint_as_float(u.x & 0xffff0000u);
    a2 += b2f(u.y & 0xffffu);
    a3 += __uint_as_float(u.y & 0xffff0000u);
  }
  float o0 = fmaxf(fmaf(a0, iv, b2f(s.x & 0xffffu)) + b4.x, 0.f);
  float o1 = fmaxf(fmaf(a1, iv, __uint_as_float(s.x & 0xffff0000u)) + b4.y, 0.f);
  float o2 = fmaxf(fmaf(a2, iv, b2f(s.y & 0xffffu)) + b4.z, 0.f);
  float o3 = fmaxf(fmaf(a3, iv, __uint_as_float(s.y & 0xffff0000u)) + b4.w, 0.f);
  if (LAST) {
    float4 o; o.x = o0; o.y = o1; o.z = o2; o.w = o3;
    ((float4*)outp)[(size_t)v * 64 + lane] = o;
  } else {
    ushort4 o; o.x = f2b(o0); o.y = f2b(o1); o.z = f2b(o2); o.w = f2b(o3);
    ((ushort4*)outp)[(size_t)v * 64 + lane] = o;
  }
}

extern "C" void kernel_launch(void* const* d_in, const int* in_sizes, int n_in,
                              void* d_out, int out_size, void* d_ws, size_t ws_size,
                              hipStream_t stream) {
  const float* X       = (const float*)d_in[0];
  const int*   ntype   = (const int*)d_in[1];
  const int*   eidx    = (const int*)d_in[2];
  const int*   etype   = (const int*)d_in[3];
  const float* adapt_W = (const float*)d_in[5];
  const float* adapt_b = (const float*)d_in[6];
  const float* W_rel   = (const float*)d_in[7];
  const float* W_self  = (const float*)d_in[8];
  const float* b_self  = (const float*)d_in[9];

  const int N = in_sizes[1];
  const int E = in_sizes[3];
  const int* src = eidx;
  const int* dst = eidx + E;

  char* ws = (char*)d_ws;
  size_t o = 0;
  auto alloc = [&](size_t bytes) { void* p = ws + o; o += (bytes + 255) & ~255ull; return p; };

  ushort* Hall  = (ushort*)alloc((size_t)N * LDH * 2);  // 71.7 MB; also aliases Xb
  ushort* Xb    = Hall;                                  // Xb dead before Hall written
  ushort* h     = (ushort*)alloc((size_t)N * D * 2);
  ushort* Wab   = (ushort*)alloc((size_t)NTYPES * D * DIN * 2);
  ushort* Wcat  = (ushort*)alloc((size_t)2 * NSLOT * D * D * 2);
  int*   deg    = (int*)alloc((size_t)N * 4);
  float* inv    = (float*)alloc((size_t)N * 4);
  int*   perm   = (int*)alloc((size_t)N * 4);
  int*   rowptr = (int*)alloc((size_t)(N + 1) * 4);
  int*   cursor = (int*)alloc((size_t)N * 4);
  int*   epack  = (int*)alloc((size_t)E * 4);
  int*   blockcnt = (int*)alloc((size_t)1024 * NTYPES * 4);
  int*   boffset  = (int*)alloc((size_t)1024 * NTYPES * 4);
  int*   cnt    = (int*)alloc(NTYPES * 4);
  int*   offt   = (int*)alloc(NTYPES * 4);

  const int thr = 256;
  const int nbN = (N + thr - 1) / thr;
  const int nbE = (E + thr - 1) / thr;

  // L0: zero deg (custom kernel; runtime fill is ~40us in-graph)
  k_zero<<<nbN, thr, 0, stream>>>(deg, N);

  // L1: mega prep — degree | type-hist | cvtX | cvtW | packWcat (one launch)
  const int n4x = N * DIN / 4;
  const int n4w = NTYPES * D * DIN / 4;
  const int nx = (n4x + thr - 1) / thr;
  const int nw = (n4w + thr - 1) / thr;
  const int np = 2 * NSLOT * (D * D / 256);
  k_prep_fused<<<nbE + nbN + nx + nw + np, thr, 0, stream>>>(
      dst, deg, ntype, blockcnt, X, Xb, adapt_W, Wab, W_rel, W_self, Wcat,
      N, E, nbE, nbN, nx, nw, n4x, n4w);

  // L2: fused scans — type_scan (block 0) | full degree scan (block 1)
  k_scan_fused<<<2, thr, 0, stream>>>(blockcnt, boffset, cnt, offt, nbN,
                                      deg, rowptr, cursor, inv, N, E);

  // L3: fused — type scatter (perm) | edge sort (epack)
  k_scatter_sort<<<nbN + nbE, thr, 0, stream>>>(ntype, boffset, perm, N, nbN,
                                                src, dst, etype, cursor, epack, E);

  // L4: adaptation h = tanh(X @ W_t^T + b_t) — 64x64 tiles, 1D swizzled grid
  const int mtA = (N + 63) / 64;
  const int nwgA = NTYPES * mtA * (D / 64);
  k_mfma_gemm<64, 64, D / 64, DIN, true, 6><<<nwgA, 256, 0, stream>>>(
      Xb, Wab, adapt_b, perm, cnt, offt, h, N, D);

  // L5-L8: two relational layers — 128x128 GEMM + CSR combine
  const int mtL = (N + 127) / 128;
  const int nwgL = mtL * (LDH / 128);
  for (int l = 0; l < 2; ++l) {
    const ushort* Wl = Wcat + (size_t)l * NSLOT * D * D;
    k_mfma_gemm<128, 128, LDH / 128, D, false, 4><<<nwgL, 256, 0, stream>>>(
        h, Wl, nullptr, nullptr, nullptr, nullptr, Hall, N, LDH);
    if (l == 0)
      k_combine<false><<<(N + 3) / 4, 256, 0, stream>>>(Hall, rowptr, epack, inv,
                                                        b_self + (size_t)l * D, h, N);
    else
      k_combine<true><<<(N + 3) / 4, 256, 0, stream>>>(Hall, rowptr, epack, inv,
                                                       b_self + (size_t)l * D, d_out, N);
  }
}

// Round 13
// 194.794 us; speedup vs baseline: 1.2363x; 1.2363x over previous
//
#include <hip/hip_runtime.h>

constexpr int NTYPES = 8;
constexpr int NREL   = 6;
constexpr int NSLOT  = 7;          // 6 relations + self
constexpr int D      = 256;
constexpr int DIN    = 512;
constexpr int LDH    = NSLOT * D;  // 1792

using short8 = __attribute__((ext_vector_type(8))) short;
using f32x4  = __attribute__((ext_vector_type(4))) float;

__device__ __forceinline__ ushort f2b(float f) {  // f32 -> bf16 RNE
  unsigned u = __float_as_uint(f);
  u += 0x7fffu + ((u >> 16) & 1u);
  return (ushort)(u >> 16);
}
__device__ __forceinline__ float b2f(unsigned bits16) {
  return __uint_as_float(bits16 << 16);
}

#define GLOAD_LDS16(g, l)                                              \
  __builtin_amdgcn_global_load_lds(                                    \
      (__attribute__((address_space(1))) void*)(g),                    \
      (__attribute__((address_space(3))) void*)(l), 16, 0, 0)

// ---------------- fused prep: zero deg | cvt X | cvt adapt_W | pack Wcat ------
__global__ void k_prep_fused(int* __restrict__ deg,
                             const float* __restrict__ X, ushort* __restrict__ Xb,
                             const float* __restrict__ Wa, ushort* __restrict__ Wab,
                             const float* __restrict__ Wrel, const float* __restrict__ Wself,
                             ushort* __restrict__ Wcat,
                             int N, int nz, int nx, int nw, int n4x, int n4w) {
  const int b = blockIdx.x;
  const int tid = threadIdx.x;
  if (b < nz) {
    int i = b * 256 + tid;
    if (i < N) deg[i] = 0;
  } else if (b < nz + nx) {
    int i = (b - nz) * 256 + tid;
    if (i < n4x) {
      float4 v = ((const float4*)X)[i];
      ushort4 o; o.x = f2b(v.x); o.y = f2b(v.y); o.z = f2b(v.z); o.w = f2b(v.w);
      ((ushort4*)Xb)[i] = o;
    }
  } else if (b < nz + nx + nw) {
    int i = (b - nz - nx) * 256 + tid;
    if (i < n4w) {
      float4 v = ((const float4*)Wa)[i];
      ushort4 o; o.x = f2b(v.x); o.y = f2b(v.y); o.z = f2b(v.z); o.w = f2b(v.w);
      ((ushort4*)Wab)[i] = o;
    }
  } else {
    int local = b - nz - nx - nw;        // 0 .. 2*7*256-1
    int l = local / (NSLOT * 256);
    int s = (local % (NSLOT * 256)) / 256;
    int o = (local % 256) * 256 + tid;   // over D*D
    int e = o >> 8, d = o & 255;
    float v = (s < NREL) ? Wrel[(((size_t)l * NREL + s) * D + d) * D + e]
                         : Wself[((size_t)l * D + d) * D + e];
    Wcat[(((size_t)l * NSLOT + s) * D + e) * D + d] = f2b(v);
  }
}

// ---- fused: per-block type histogram (ballot) | degree atomics ----
__global__ void k_count_fused(const int* __restrict__ ntype, int* __restrict__ blockcnt,
                              const int* __restrict__ dst, int* __restrict__ deg,
                              int N, int E, int nbN) {
  __shared__ int cnt[NTYPES];
  const int b = blockIdx.x;
  if (b < nbN) {
    int i = b * 256 + threadIdx.x;
    if (threadIdx.x < NTYPES) cnt[threadIdx.x] = 0;
    __syncthreads();
    int t = (i < N) ? ntype[i] : -1;
#pragma unroll
    for (int ty = 0; ty < NTYPES; ++ty) {
      unsigned long long m = __ballot(t == ty);
      if ((threadIdx.x & 63) == 0 && m) atomicAdd(&cnt[ty], __popcll(m));
    }
    __syncthreads();
    if (threadIdx.x < NTYPES) blockcnt[b * NTYPES + threadIdx.x] = cnt[threadIdx.x];
  } else {
    int e = (b - nbN) * 256 + threadIdx.x;
    if (e < E) atomicAdd(&deg[dst[e]], 1);
  }
}

// ---- wave-parallel type scan: 8 waves, wave w owns type w (round-12 lesson:
// serial 79-iteration global-latency loops cost ~20-60us; shfl scans are ~3us) ----
__global__ __launch_bounds__(512)
void k_type_scan(const int* __restrict__ blockcnt, int* __restrict__ boffset,
                 int* __restrict__ cnt, int* __restrict__ offt, int nb) {
  __shared__ int tot[NTYPES];
  __shared__ int base[NTYPES];
  const int w = threadIdx.x >> 6;   // type
  const int l = threadIdx.x & 63;
  // two chunks cover nb <= 128 (nbN = 79)
  int v0 = (l < nb) ? blockcnt[l * NTYPES + w] : 0;
  int v1 = (64 + l < nb) ? blockcnt[(64 + l) * NTYPES + w] : 0;
  int s0 = v0;
#pragma unroll
  for (int o = 1; o < 64; o <<= 1) { int t = __shfl_up(s0, o); if (l >= o) s0 += t; }
  int total0 = __shfl(s0, 63);
  int s1 = v1;
#pragma unroll
  for (int o = 1; o < 64; o <<= 1) { int t = __shfl_up(s1, o); if (l >= o) s1 += t; }
  s1 += total0;
  int totalw = __shfl(s1, 63);
  if (l == 0) { tot[w] = totalw; cnt[w] = totalw; }
  __syncthreads();
  if (threadIdx.x == 0) {
    int s = 0;
    for (int ty = 0; ty < NTYPES; ++ty) { base[ty] = s; offt[ty] = s; s += tot[ty]; }
  }
  __syncthreads();
  const int bs = base[w];
  if (l < nb) boffset[l * NTYPES + w] = bs + s0 - v0;            // exclusive
  if (64 + l < nb) boffset[(64 + l) * NTYPES + w] = bs + s1 - v1;
}

// ---- fused: type scatter (perm) | degree block-scan (rowptr partials) ----
__global__ void k_scatter_scan(const int* __restrict__ ntype, const int* __restrict__ boffset,
                               int* __restrict__ perm,
                               const int* __restrict__ deg, int* __restrict__ rowptr,
                               int* __restrict__ bsum, int N, int nbN) {
  __shared__ int sm[256];
  const int b = blockIdx.x;
  if (b < nbN) {
    int i = b * 256 + threadIdx.x;
    if (threadIdx.x < NTYPES) sm[threadIdx.x] = boffset[b * NTYPES + threadIdx.x];
    __syncthreads();
    int t = (i < N) ? ntype[i] : -1;
    int lane = threadIdx.x & 63;
#pragma unroll
    for (int ty = 0; ty < NTYPES; ++ty) {
      unsigned long long m = __ballot(t == ty);
      if (m) {
        int wbase = 0;
        if (lane == 0) wbase = atomicAdd(&sm[ty], __popcll(m));
        wbase = __shfl(wbase, 0);
        if (t == ty) {
          int rank = __popcll(m & ((1ull << lane) - 1ull));
          perm[wbase + rank] = i;
        }
      }
    }
  } else {
    const int bb = b - nbN;
    int i = bb * 256 + threadIdx.x;
    int v = (i < N) ? deg[i] : 0;
    sm[threadIdx.x] = v;
    __syncthreads();
    for (int o = 1; o < 256; o <<= 1) {
      int t = (threadIdx.x >= o) ? sm[threadIdx.x - o] : 0;
      __syncthreads();
      sm[threadIdx.x] += t;
      __syncthreads();
    }
    if (i < N) rowptr[i] = sm[threadIdx.x] - v;   // exclusive within block
    if (threadIdx.x == 255) bsum[bb] = sm[255];
  }
}

// ---- wave-parallel exclusive scan of the 79 block sums ----
__global__ __launch_bounds__(64)
void k_scan_bsum(int* __restrict__ bsum, int nb) {
  const int l = threadIdx.x;
  int v0 = (l < nb) ? bsum[l] : 0;
  int v1 = (64 + l < nb) ? bsum[64 + l] : 0;
  int s0 = v0;
#pragma unroll
  for (int o = 1; o < 64; o <<= 1) { int t = __shfl_up(s0, o); if (l >= o) s0 += t; }
  int total0 = __shfl(s0, 63);
  int s1 = v1;
#pragma unroll
  for (int o = 1; o < 64; o <<= 1) { int t = __shfl_up(s1, o); if (l >= o) s1 += t; }
  s1 += total0;
  if (l < nb) bsum[l] = s0 - v0;              // exclusive
  if (64 + l < nb) bsum[64 + l] = s1 - v1;
}

// adds block offsets AND computes inv_deg in the same pass
__global__ void k_scan_add(int* __restrict__ rowptr, int* __restrict__ cursor,
                           const int* __restrict__ bsum, const int* __restrict__ deg,
                           float* __restrict__ inv, int N, int E) {
  int i = blockIdx.x * 256 + threadIdx.x;
  if (i < N) {
    int r = rowptr[i] + bsum[blockIdx.x];
    rowptr[i] = r;
    cursor[i] = r;
    inv[i] = 1.0f / fmaxf((float)deg[i], 1.0f);
  }
  if (i == 0) rowptr[N] = E;
}
__global__ void k_sortedges(const int* __restrict__ src, const int* __restrict__ dst,
                            const int* __restrict__ et, int* cursor,
                            int* __restrict__ epack, int E) {
  int e = blockIdx.x * 256 + threadIdx.x;
  if (e < E) {
    int pos = atomicAdd(&cursor[dst[e]], 1);
    epack[pos] = (src[e] << 3) | et[e];
  }
}

// ---------------- MFMA GEMM (1D swizzled grid, LDS-staged epilogue) -------------
// C[m][n] = sum_k A[m][k] * B[n][k]   (B stored row-per-output-col, k-contiguous)
// BMxBN tile, 4 waves (2x2), BK=32, bf16 in / f32 acc / bf16 out.
// 1D grid, n-tile fastest, bijective XCD swizzle (T1/m204).
// K-loop barriers are REAL __syncthreads() (IR fence + vmcnt/lgkmcnt drain +
// s_barrier); raw s_barrier is IntrNoMem and let STAGE hoist (rounds 6-7 bugs).
template <int BM, int BN, int NTN, int KDIM, bool ADAPT, int OCC>
__global__ __launch_bounds__(256, OCC)
void k_mfma_gemm(const ushort* __restrict__ A, const ushort* __restrict__ B,
                 const float* __restrict__ bias,
                 const int* __restrict__ perm, const int* __restrict__ cnt,
                 const int* __restrict__ off,
                 ushort* __restrict__ Cout, int N, int ldC) {
  // bijective XCD swizzle (works for any nwg)
  const int nwg = gridDim.x;
  const int qq = nwg >> 3, rr = nwg & 7;
  const int xcd = blockIdx.x & 7, idx = blockIdx.x >> 3;
  const int wgid = (xcd < rr ? xcd * (qq + 1) : rr * (qq + 1) + (xcd - rr) * qq) + idx;

  int mcnt = N, mtile, ntile;
  const int* permt = nullptr;
  const ushort* Bt = B;
  const float* biast = bias;
  if (ADAPT) {
    const int mt = nwg / (NTYPES * NTN);
    const int t = wgid / (mt * NTN);
    const int rem = wgid % (mt * NTN);
    mtile = rem / NTN;
    ntile = rem % NTN;
    mcnt = cnt[t];
    permt = perm + off[t];
    Bt = B + (size_t)t * D * KDIM;
    biast = bias + t * D;
  } else {
    mtile = wgid / NTN;
    ntile = wgid % NTN;
  }
  const int m0 = mtile * BM;
  if (m0 >= mcnt) return;
  const int n0 = ntile * BN;

  __shared__ ushort SM[2][2][BM * 32];   // [buf][A=0/B=1][row*32+k]
  static_assert(BM * BN <= 2 * 2 * BM * 32, "C tile must fit in staging LDS");

  const int tid  = threadIdx.x;
  const int lane = tid & 63;
  const int w    = tid >> 6;
  constexpr int FR = BM / 32;
  constexpr int FC = BN / 32;
  const int wr   = (w >> 1) * (BM / 2);
  const int wc   = (w & 1) * (BN / 2);

  // staging: (BM/16) x 1KB calls per matrix; wave w does calls {w, w+4, ...}.
  // XOR swizzle on GLOBAL source slot (LDS dest linear), undone at ds_read.
  constexpr int PW = BM / 16 / 4;
  const ushort* gA[PW];
  const ushort* gB[PW];
  int lo[PW];
#pragma unroll
  for (int u = 0; u < PW; ++u) {
    const int c  = w + u * 4;
    const int r  = c * 16 + (lane >> 2);
    const int sl = (lane & 3) ^ ((r >> 1) & 3);
    int ga;
    if (ADAPT) ga = permt[min(m0 + r, mcnt - 1)];
    else       ga = min(m0 + r, N - 1);
    gA[u] = A + (size_t)ga * KDIM + sl * 8;
    gB[u] = Bt + (size_t)(n0 + r) * KDIM + sl * 8;
    lo[u] = c * 512;
  }

  auto STAGE = [&](int k0, int buf) {
#pragma unroll
    for (int u = 0; u < PW; ++u) {
      GLOAD_LDS16(gA[u] + k0, &SM[buf][0][lo[u]]);
      GLOAD_LDS16(gB[u] + k0, &SM[buf][1][lo[u]]);
    }
  };

  f32x4 acc[FR][FC] = {};
  const int r15 = lane & 15;
  const int g   = lane >> 4;
  const int gsw = g ^ ((r15 >> 1) & 3);

  STAGE(0, 0);
  __syncthreads();

  constexpr int NT = KDIM / 32;
  int curb = 0;
#pragma unroll
  for (int kt = 0; kt < NT; ++kt) {
    if (kt + 1 < NT) STAGE((kt + 1) * 32, curb ^ 1);   // prefetch next tile

    short8 af[FR], bf[FC];
#pragma unroll
    for (int i = 0; i < FR; ++i)
      af[i] = *(const short8*)(&SM[curb][0][(wr + i * 16 + r15) * 32 + gsw * 8]);
#pragma unroll
    for (int j = 0; j < FC; ++j)
      bf[j] = *(const short8*)(&SM[curb][1][(wc + j * 16 + r15) * 32 + gsw * 8]);
#pragma unroll
    for (int i = 0; i < FR; ++i)
#pragma unroll
      for (int j = 0; j < FC; ++j)
        acc[i][j] = __builtin_amdgcn_mfma_f32_16x16x32_bf16(af[i], bf[j], acc[i][j], 0, 0, 0);

    __syncthreads();   // real fence+barrier: prefetch landed, reads joined
    curb ^= 1;
  }

  // ---- epilogue: C/D layout (m89): col = lane&15, row = (lane>>4)*4 + reg ----
  ushort* Ct = (ushort*)SM;
#pragma unroll
  for (int i = 0; i < FR; ++i) {
#pragma unroll
    for (int q4 = 0; q4 < 4; ++q4) {
      const int row = wr + i * 16 + (lane >> 4) * 4 + q4;
#pragma unroll
      for (int j = 0; j < FC; ++j) {
        const int col = wc + j * 16 + r15;
        float v = acc[i][j][q4];
        if (ADAPT) v = tanhf(v + biast[n0 + col]);
        Ct[row * BN + col] = f2b(v);
      }
    }
  }
  __syncthreads();
  constexpr int C8 = BN / 8;
  constexpr int UNITS = BM * C8;
#pragma unroll
  for (int u0 = 0; u0 < UNITS; u0 += 256) {
    const int u = u0 + tid;
    const int row = u / C8, c8 = u % C8;
    const int rl = m0 + row;
    if (rl < mcnt) {
      const int grow = ADAPT ? permt[rl] : rl;
      *(short8*)(Cout + (size_t)grow * ldC + n0 + c8 * 8) =
          *(const short8*)(Ct + row * BN + c8 * 8);
    }
  }
}

// ---------------- CSR gather-combine ----------------
// out[v] = relu( (sum_{e in in(v)} Hall[src_e][rel_e*256 + :]) * inv[v]
//                + Hall[v][6*256 + :] + bias )
// one wave per node, lane owns 4 channels; edge loop 8-wide unrolled so 8
// independent L2/L3 gathers are in flight per wave.
template <bool LAST>
__global__ void k_combine(const ushort* __restrict__ Hall, const int* __restrict__ rowptr,
                          const int* __restrict__ epack, const float* __restrict__ invd,
                          const float* __restrict__ bias, void* __restrict__ outp, int N) {
  int v = blockIdx.x * 4 + (threadIdx.x >> 6);
  if (v >= N) return;
  int lane = threadIdx.x & 63;
  int e0 = rowptr[v], e1 = rowptr[v + 1];
  const uint2 s = *(const uint2*)(Hall + (size_t)v * LDH + NREL * D + lane * 4);
  float iv = invd[v];
  const float4 b4 = *(const float4*)(bias + lane * 4);

  float a0 = 0.f, a1 = 0.f, a2 = 0.f, a3 = 0.f;
  int e = e0;
  for (; e + 8 <= e1; e += 8) {
    uint2 u[8];
#pragma unroll
    for (int k = 0; k < 8; ++k) {
      int p = epack[e + k];
      u[k] = *(const uint2*)(Hall + (size_t)(p >> 3) * LDH + (p & 7) * D + lane * 4);
    }
#pragma unroll
    for (int k = 0; k < 8; ++k) {
      a0 += b2f(u[k].x & 0xffffu);
      a1 += __uint_as_float(u[k].x & 0xffff0000u);
      a2 += b2f(u[k].y & 0xffffu);
      a3 += __uint_as_float(u[k].y & 0xffff0000u);
    }
  }
  if (e + 4 <= e1) {
    uint2 u[4];
#pragma unroll
    for (int k = 0; k < 4; ++k) {
      int p = epack[e + k];
      u[k] = *(const uint2*)(Hall + (size_t)(p >> 3) * LDH + (p & 7) * D + lane * 4);
    }
#pragma unroll
    for (int k = 0; k < 4; ++k) {
      a0 += b2f(u[k].x & 0xffffu);
      a1 += __uint_as_float(u[k].x & 0xffff0000u);
      a2 += b2f(u[k].y & 0xffffu);
      a3 += __uint_as_float(u[k].y & 0xffff0000u);
    }
    e += 4;
  }
  for (; e < e1; ++e) {
    int p = epack[e];
    const uint2 u = *(const uint2*)(Hall + (size_t)(p >> 3) * LDH + (p & 7) * D + lane * 4);
    a0 += b2f(u.x & 0xffffu);
    a1 += __uint_as_float(u.x & 0xffff0000u);
    a2 += b2f(u.y & 0xffffu);
    a3 += __uint_as_float(u.y & 0xffff0000u);
  }
  float o0 = fmaxf(fmaf(a0, iv, b2f(s.x & 0xffffu)) + b4.x, 0.f);
  float o1 = fmaxf(fmaf(a1, iv, __uint_as_float(s.x & 0xffff0000u)) + b4.y, 0.f);
  float o2 = fmaxf(fmaf(a2, iv, b2f(s.y & 0xffffu)) + b4.z, 0.f);
  float o3 = fmaxf(fmaf(a3, iv, __uint_as_float(s.y & 0xffff0000u)) + b4.w, 0.f);
  if (LAST) {
    float4 o; o.x = o0; o.y = o1; o.z = o2; o.w = o3;
    ((float4*)outp)[(size_t)v * 64 + lane] = o;
  } else {
    ushort4 o; o.x = f2b(o0); o.y = f2b(o1); o.z = f2b(o2); o.w = f2b(o3);
    ((ushort4*)outp)[(size_t)v * 64 + lane] = o;
  }
}

extern "C" void kernel_launch(void* const* d_in, const int* in_sizes, int n_in,
                              void* d_out, int out_size, void* d_ws, size_t ws_size,
                              hipStream_t stream) {
  const float* X       = (const float*)d_in[0];
  const int*   ntype   = (const int*)d_in[1];
  const int*   eidx    = (const int*)d_in[2];
  const int*   etype   = (const int*)d_in[3];
  const float* adapt_W = (const float*)d_in[5];
  const float* adapt_b = (const float*)d_in[6];
  const float* W_rel   = (const float*)d_in[7];
  const float* W_self  = (const float*)d_in[8];
  const float* b_self  = (const float*)d_in[9];

  const int N = in_sizes[1];
  const int E = in_sizes[3];
  const int* src = eidx;
  const int* dst = eidx + E;

  char* ws = (char*)d_ws;
  size_t o = 0;
  auto alloc = [&](size_t bytes) { void* p = ws + o; o += (bytes + 255) & ~255ull; return p; };

  ushort* Hall  = (ushort*)alloc((size_t)N * LDH * 2);  // 71.7 MB; also aliases Xb
  ushort* Xb    = Hall;                                  // Xb dead before Hall written
  ushort* h     = (ushort*)alloc((size_t)N * D * 2);
  ushort* Wab   = (ushort*)alloc((size_t)NTYPES * D * DIN * 2);
  ushort* Wcat  = (ushort*)alloc((size_t)2 * NSLOT * D * D * 2);
  int*   deg    = (int*)alloc((size_t)N * 4);
  float* inv    = (float*)alloc((size_t)N * 4);
  int*   perm   = (int*)alloc((size_t)N * 4);
  int*   rowptr = (int*)alloc((size_t)(N + 1) * 4);
  int*   cursor = (int*)alloc((size_t)N * 4);
  int*   epack  = (int*)alloc((size_t)E * 4);
  int*   bsum   = (int*)alloc(1024 * 4);
  int*   blockcnt = (int*)alloc((size_t)1024 * NTYPES * 4);
  int*   boffset  = (int*)alloc((size_t)1024 * NTYPES * 4);
  int*   cnt    = (int*)alloc(NTYPES * 4);
  int*   offt   = (int*)alloc(NTYPES * 4);

  const int thr = 256;
  const int nbN = (N + thr - 1) / thr;
  const int nbE = (E + thr - 1) / thr;

  // fused prep: zero deg | X->bf16 | adapt_W->bf16 | pack Wcat  (1 launch)
  const int n4x = N * DIN / 4;
  const int n4w = NTYPES * D * DIN / 4;
  const int nz = nbN;
  const int nx = (n4x + thr - 1) / thr;
  const int nw = (n4w + thr - 1) / thr;
  const int np = 2 * NSLOT * (D * D / 256);
  k_prep_fused<<<nz + nx + nw + np, thr, 0, stream>>>(deg, X, Xb, adapt_W, Wab,
                                                      W_rel, W_self, Wcat,
                                                      N, nz, nx, nw, n4x, n4w);

  // fused: type histogram | degree atomics  (1 launch)
  k_count_fused<<<nbN + nbE, thr, 0, stream>>>(ntype, blockcnt, dst, deg, N, E, nbN);
  k_type_scan<<<1, 512, 0, stream>>>(blockcnt, boffset, cnt, offt, nbN);
  // fused: type scatter | degree block-scan  (1 launch)
  k_scatter_scan<<<2 * nbN, thr, 0, stream>>>(ntype, boffset, perm, deg, rowptr, bsum, N, nbN);
  k_scan_bsum<<<1, 64, 0, stream>>>(bsum, nbN);
  k_scan_add<<<nbN, 256, 0, stream>>>(rowptr, cursor, bsum, deg, inv, N, E);
  k_sortedges<<<nbE, 256, 0, stream>>>(src, dst, etype, cursor, epack, E);

  // adaptation: h = tanh(X @ W_t^T + b_t), bf16 — 64x64 tiles, 1D swizzled grid
  const int mtA = (N + 63) / 64;
  const int nwgA = NTYPES * mtA * (D / 64);
  k_mfma_gemm<64, 64, D / 64, DIN, true, 6><<<nwgA, 256, 0, stream>>>(
      Xb, Wab, adapt_b, perm, cnt, offt, h, N, D);

  // two relational layers — 128x128 tiles, n-fast 1D grid + XCD swizzle
  const int mtL = (N + 127) / 128;
  const int nwgL = mtL * (LDH / 128);
  for (int l = 0; l < 2; ++l) {
    const ushort* Wl = Wcat + (size_t)l * NSLOT * D * D;
    k_mfma_gemm<128, 128, LDH / 128, D, false, 4><<<nwgL, 256, 0, stream>>>(
        h, Wl, nullptr, nullptr, nullptr, nullptr, Hall, N, LDH);
    if (l == 0)
      k_combine<false><<<(N + 3) / 4, 256, 0, stream>>>(Hall, rowptr, epack, inv,
                                                        b_self + (size_t)l * D, h, N);
    else
      k_combine<true><<<(N + 3) / 4, 256, 0, stream>>>(Hall, rowptr, epack, inv,
                                                       b_self + (size_t)l * D, d_out, N);
  }
}

// Round 14
// 191.453 us; speedup vs baseline: 1.2578x; 1.0174x over previous
//
#include <hip/hip_runtime.h>

constexpr int NTYPES = 8;
constexpr int NREL   = 6;
constexpr int NSLOT  = 7;          // 6 relations + self
constexpr int D      = 256;
constexpr int DIN    = 512;
constexpr int LDH    = NSLOT * D;  // 1792

using short8 = __attribute__((ext_vector_type(8))) short;
using f32x4  = __attribute__((ext_vector_type(4))) float;

__device__ __forceinline__ ushort f2b(float f) {  // f32 -> bf16 RNE
  unsigned u = __float_as_uint(f);
  u += 0x7fffu + ((u >> 16) & 1u);
  return (ushort)(u >> 16);
}
__device__ __forceinline__ float b2f(unsigned bits16) {
  return __uint_as_float(bits16 << 16);
}

#define GLOAD_LDS16(g, l)                                              \
  __builtin_amdgcn_global_load_lds(                                    \
      (__attribute__((address_space(1))) void*)(g),                    \
      (__attribute__((address_space(3))) void*)(l), 16, 0, 0)

// ---------------- fused prep: zero deg | cvt X | cvt adapt_W | pack Wcat ------
__global__ void k_prep_fused(int* __restrict__ deg,
                             const float* __restrict__ X, ushort* __restrict__ Xb,
                             const float* __restrict__ Wa, ushort* __restrict__ Wab,
                             const float* __restrict__ Wrel, const float* __restrict__ Wself,
                             ushort* __restrict__ Wcat,
                             int N, int nz, int nx, int nw, int n4x, int n4w) {
  const int b = blockIdx.x;
  const int tid = threadIdx.x;
  if (b < nz) {
    int i = b * 256 + tid;
    if (i < N) deg[i] = 0;
  } else if (b < nz + nx) {
    int i = (b - nz) * 256 + tid;
    if (i < n4x) {
      float4 v = ((const float4*)X)[i];
      ushort4 o; o.x = f2b(v.x); o.y = f2b(v.y); o.z = f2b(v.z); o.w = f2b(v.w);
      ((ushort4*)Xb)[i] = o;
    }
  } else if (b < nz + nx + nw) {
    int i = (b - nz - nx) * 256 + tid;
    if (i < n4w) {
      float4 v = ((const float4*)Wa)[i];
      ushort4 o; o.x = f2b(v.x); o.y = f2b(v.y); o.z = f2b(v.z); o.w = f2b(v.w);
      ((ushort4*)Wab)[i] = o;
    }
  } else {
    int local = b - nz - nx - nw;        // 0 .. 2*7*256-1
    int l = local / (NSLOT * 256);
    int s = (local % (NSLOT * 256)) / 256;
    int o = (local % 256) * 256 + tid;   // over D*D
    int e = o >> 8, d = o & 255;
    float v = (s < NREL) ? Wrel[(((size_t)l * NREL + s) * D + d) * D + e]
                         : Wself[((size_t)l * D + d) * D + e];
    Wcat[(((size_t)l * NSLOT + s) * D + e) * D + d] = f2b(v);
  }
}

// ---- fused: per-block type histogram (ballot) | degree atomics ----
__global__ void k_count_fused(const int* __restrict__ ntype, int* __restrict__ blockcnt,
                              const int* __restrict__ dst, int* __restrict__ deg,
                              int N, int E, int nbN) {
  __shared__ int cnt[NTYPES];
  const int b = blockIdx.x;
  if (b < nbN) {
    int i = b * 256 + threadIdx.x;
    if (threadIdx.x < NTYPES) cnt[threadIdx.x] = 0;
    __syncthreads();
    int t = (i < N) ? ntype[i] : -1;
#pragma unroll
    for (int ty = 0; ty < NTYPES; ++ty) {
      unsigned long long m = __ballot(t == ty);
      if ((threadIdx.x & 63) == 0 && m) atomicAdd(&cnt[ty], __popcll(m));
    }
    __syncthreads();
    if (threadIdx.x < NTYPES) blockcnt[b * NTYPES + threadIdx.x] = cnt[threadIdx.x];
  } else {
    int e = (b - nbN) * 256 + threadIdx.x;
    if (e < E) atomicAdd(&deg[dst[e]], 1);
  }
}

// ---- wave-parallel type scan: 8 waves, wave w owns type w ----
__global__ __launch_bounds__(512)
void k_type_scan(const int* __restrict__ blockcnt, int* __restrict__ boffset,
                 int* __restrict__ cnt, int* __restrict__ offt, int nb) {
  __shared__ int tot[NTYPES];
  __shared__ int base[NTYPES];
  const int w = threadIdx.x >> 6;   // type
  const int l = threadIdx.x & 63;
  int v0 = (l < nb) ? blockcnt[l * NTYPES + w] : 0;
  int v1 = (64 + l < nb) ? blockcnt[(64 + l) * NTYPES + w] : 0;
  int s0 = v0;
#pragma unroll
  for (int o = 1; o < 64; o <<= 1) { int t = __shfl_up(s0, o); if (l >= o) s0 += t; }
  int total0 = __shfl(s0, 63);
  int s1 = v1;
#pragma unroll
  for (int o = 1; o < 64; o <<= 1) { int t = __shfl_up(s1, o); if (l >= o) s1 += t; }
  s1 += total0;
  int totalw = __shfl(s1, 63);
  if (l == 0) { tot[w] = totalw; cnt[w] = totalw; }
  __syncthreads();
  if (threadIdx.x == 0) {
    int s = 0;
    for (int ty = 0; ty < NTYPES; ++ty) { base[ty] = s; offt[ty] = s; s += tot[ty]; }
  }
  __syncthreads();
  const int bs = base[w];
  if (l < nb) boffset[l * NTYPES + w] = bs + s0 - v0;            // exclusive
  if (64 + l < nb) boffset[(64 + l) * NTYPES + w] = bs + s1 - v1;
}

// ---- fused: type scatter (perm) | degree block-scan (rowptr partials) ----
__global__ void k_scatter_scan(const int* __restrict__ ntype, const int* __restrict__ boffset,
                               int* __restrict__ perm,
                               const int* __restrict__ deg, int* __restrict__ rowptr,
                               int* __restrict__ bsum, int N, int nbN) {
  __shared__ int sm[256];
  const int b = blockIdx.x;
  if (b < nbN) {
    int i = b * 256 + threadIdx.x;
    if (threadIdx.x < NTYPES) sm[threadIdx.x] = boffset[b * NTYPES + threadIdx.x];
    __syncthreads();
    int t = (i < N) ? ntype[i] : -1;
    int lane = threadIdx.x & 63;
#pragma unroll
    for (int ty = 0; ty < NTYPES; ++ty) {
      unsigned long long m = __ballot(t == ty);
      if (m) {
        int wbase = 0;
        if (lane == 0) wbase = atomicAdd(&sm[ty], __popcll(m));
        wbase = __shfl(wbase, 0);
        if (t == ty) {
          int rank = __popcll(m & ((1ull << lane) - 1ull));
          perm[wbase + rank] = i;
        }
      }
    }
  } else {
    const int bb = b - nbN;
    int i = bb * 256 + threadIdx.x;
    int v = (i < N) ? deg[i] : 0;
    sm[threadIdx.x] = v;
    __syncthreads();
    for (int o = 1; o < 256; o <<= 1) {
      int t = (threadIdx.x >= o) ? sm[threadIdx.x - o] : 0;
      __syncthreads();
      sm[threadIdx.x] += t;
      __syncthreads();
    }
    if (i < N) rowptr[i] = sm[threadIdx.x] - v;   // exclusive within block
    if (threadIdx.x == 255) bsum[bb] = sm[255];
  }
}

// ---- wave-parallel exclusive scan of the 79 block sums ----
__global__ __launch_bounds__(64)
void k_scan_bsum(int* __restrict__ bsum, int nb) {
  const int l = threadIdx.x;
  int v0 = (l < nb) ? bsum[l] : 0;
  int v1 = (64 + l < nb) ? bsum[64 + l] : 0;
  int s0 = v0;
#pragma unroll
  for (int o = 1; o < 64; o <<= 1) { int t = __shfl_up(s0, o); if (l >= o) s0 += t; }
  int total0 = __shfl(s0, 63);
  int s1 = v1;
#pragma unroll
  for (int o = 1; o < 64; o <<= 1) { int t = __shfl_up(s1, o); if (l >= o) s1 += t; }
  s1 += total0;
  if (l < nb) bsum[l] = s0 - v0;              // exclusive
  if (64 + l < nb) bsum[64 + l] = s1 - v1;
}

// adds block offsets AND computes inv_deg in the same pass
__global__ void k_scan_add(int* __restrict__ rowptr, int* __restrict__ cursor,
                           const int* __restrict__ bsum, const int* __restrict__ deg,
                           float* __restrict__ inv, int N, int E) {
  int i = blockIdx.x * 256 + threadIdx.x;
  if (i < N) {
    int r = rowptr[i] + bsum[blockIdx.x];
    rowptr[i] = r;
    cursor[i] = r;
    inv[i] = 1.0f / fmaxf((float)deg[i], 1.0f);
  }
  if (i == 0) rowptr[N] = E;
}
__global__ void k_sortedges(const int* __restrict__ src, const int* __restrict__ dst,
                            const int* __restrict__ et, int* cursor,
                            int* __restrict__ epack, int E) {
  int e = blockIdx.x * 256 + threadIdx.x;
  if (e < E) {
    int pos = atomicAdd(&cursor[dst[e]], 1);
    epack[pos] = (src[e] << 3) | et[e];
  }
}

// ---------------- MFMA GEMM: T4 counted-vmcnt 3-buffer pipeline ----------------
// C[m][n] = sum_k A[m][k] * B[n][k]   (B stored row-per-output-col, k-contiguous)
// BMxBN tile, 4 waves (2x2), BK=32, bf16 in / f32 acc / bf16 out.
// Round-13 diagnosis: __syncthreads drains vmcnt(0), so the same-iteration
// prefetch completes before the next iter -> full HBM latency exposed per iter
// (MfmaUtil 17%). Fix (guide T4): 3 LDS buffers; per iter wait only the
// 2-iter-old stage via counted s_waitcnt vmcnt(LPS); newer stage stays in
// flight ACROSS the raw s_barrier. sched_barrier(0) immediately after each
// s_barrier blocks STAGE/ds_read hoisting above it (the rounds-6/7 race).
// Each wave waits its own vmcnt; barrier then joins -> all waves' stage(t)
// LDS writes visible. Epilogue guarded by a real __syncthreads (IR fence).
template <int BM, int BN, int NTN, int KDIM, bool ADAPT, int OCC>
__global__ __launch_bounds__(256, OCC)
void k_mfma_gemm(const ushort* __restrict__ A, const ushort* __restrict__ B,
                 const float* __restrict__ bias,
                 const int* __restrict__ perm, const int* __restrict__ cnt,
                 const int* __restrict__ off,
                 ushort* __restrict__ Cout, int N, int ldC) {
  // bijective XCD swizzle (works for any nwg)
  const int nwg = gridDim.x;
  const int qq = nwg >> 3, rr = nwg & 7;
  const int xcd = blockIdx.x & 7, idx = blockIdx.x >> 3;
  const int wgid = (xcd < rr ? xcd * (qq + 1) : rr * (qq + 1) + (xcd - rr) * qq) + idx;

  int mcnt = N, mtile, ntile;
  const int* permt = nullptr;
  const ushort* Bt = B;
  const float* biast = bias;
  if (ADAPT) {
    const int mt = nwg / (NTYPES * NTN);
    const int t = wgid / (mt * NTN);
    const int rem = wgid % (mt * NTN);
    mtile = rem / NTN;
    ntile = rem % NTN;
    mcnt = cnt[t];
    permt = perm + off[t];
    Bt = B + (size_t)t * D * KDIM;
    biast = bias + t * D;
  } else {
    mtile = wgid / NTN;
    ntile = wgid % NTN;
  }
  const int m0 = mtile * BM;
  if (m0 >= mcnt) return;
  const int n0 = ntile * BN;

  __shared__ ushort SM[3][2][BM * 32];   // [buf][A=0/B=1][row*32+k]
  static_assert(BM * BN <= 3 * 2 * BM * 32, "C tile must fit in staging LDS");

  const int tid  = threadIdx.x;
  const int lane = tid & 63;
  const int w    = tid >> 6;
  constexpr int FR = BM / 32;
  constexpr int FC = BN / 32;
  const int wr   = (w >> 1) * (BM / 2);
  const int wc   = (w & 1) * (BN / 2);

  // staging: (BM/16) x 1KB calls per matrix; wave w does calls {w, w+4, ...}.
  // XOR swizzle on GLOBAL source slot (LDS dest linear), undone at ds_read.
  constexpr int PW = BM / 16 / 4;        // calls per wave per matrix (1 or 2)
  const ushort* gA[PW];
  const ushort* gB[PW];
  int lo[PW];
#pragma unroll
  for (int u = 0; u < PW; ++u) {
    const int c  = w + u * 4;
    const int r  = c * 16 + (lane >> 2);
    const int sl = (lane & 3) ^ ((r >> 1) & 3);
    int ga;
    if (ADAPT) ga = permt[min(m0 + r, mcnt - 1)];
    else       ga = min(m0 + r, N - 1);
    gA[u] = A + (size_t)ga * KDIM + sl * 8;
    gB[u] = Bt + (size_t)(n0 + r) * KDIM + sl * 8;
    lo[u] = c * 512;
  }

  auto STAGE = [&](int k0, int buf) {
#pragma unroll
    for (int u = 0; u < PW; ++u) {
      GLOAD_LDS16(gA[u] + k0, &SM[buf][0][lo[u]]);
      GLOAD_LDS16(gB[u] + k0, &SM[buf][1][lo[u]]);
    }
  };
  // wait until only the newest stage (LPS = PW*2 loads) may be outstanding
  auto WAIT_LPS = [&]() {
    if constexpr (PW == 1) asm volatile("s_waitcnt vmcnt(2)" ::: "memory");
    else                   asm volatile("s_waitcnt vmcnt(4)" ::: "memory");
  };

  f32x4 acc[FR][FC] = {};
  const int r15 = lane & 15;
  const int g   = lane >> 4;
  const int gsw = g ^ ((r15 >> 1) & 3);

  auto COMPUTE = [&](int buf) {
    short8 af[FR], bf[FC];
#pragma unroll
    for (int i = 0; i < FR; ++i)
      af[i] = *(const short8*)(&SM[buf][0][(wr + i * 16 + r15) * 32 + gsw * 8]);
#pragma unroll
    for (int j = 0; j < FC; ++j)
      bf[j] = *(const short8*)(&SM[buf][1][(wc + j * 16 + r15) * 32 + gsw * 8]);
#pragma unroll
    for (int i = 0; i < FR; ++i)
#pragma unroll
      for (int j = 0; j < FC; ++j)
        acc[i][j] = __builtin_amdgcn_mfma_f32_16x16x32_bf16(af[i], bf[j], acc[i][j], 0, 0, 0);
  };

  constexpr int NT = KDIM / 32;
  static_assert(NT >= 3, "pipeline needs NT >= 3");

  // prologue: two stages in flight
  STAGE(0, 0);
  STAGE(32, 1);

#pragma unroll
  for (int kt = 0; kt < NT - 1; ++kt) {
    WAIT_LPS();                               // stage(kt) landed; stage(kt+1) in flight
    __builtin_amdgcn_s_barrier();             // all waves' stage(kt) visible
    __builtin_amdgcn_sched_barrier(0);        // nothing hoists above the barrier
    COMPUTE(kt % 3);
    if (kt + 2 < NT) STAGE((kt + 2) * 32, (kt + 2) % 3);  // overwrites buf read @ kt-1
  }
  // final iteration: drain everything
  asm volatile("s_waitcnt vmcnt(0)" ::: "memory");
  __builtin_amdgcn_s_barrier();
  __builtin_amdgcn_sched_barrier(0);
  COMPUTE((NT - 1) % 3);

  // ---- epilogue: C/D layout (m89): col = lane&15, row = (lane>>4)*4 + reg ----
  // real __syncthreads: IR fence + barrier so Ct writes (aliasing SM) cannot
  // overlap any wave's final-buffer reads.
  __syncthreads();
  ushort* Ct = (ushort*)SM;
#pragma unroll
  for (int i = 0; i < FR; ++i) {
#pragma unroll
    for (int q4 = 0; q4 < 4; ++q4) {
      const int row = wr + i * 16 + (lane >> 4) * 4 + q4;
#pragma unroll
      for (int j = 0; j < FC; ++j) {
        const int col = wc + j * 16 + r15;
        float v = acc[i][j][q4];
        if (ADAPT) v = tanhf(v + biast[n0 + col]);
        Ct[row * BN + col] = f2b(v);
      }
    }
  }
  __syncthreads();
  constexpr int C8 = BN / 8;
  constexpr int UNITS = BM * C8;
#pragma unroll
  for (int u0 = 0; u0 < UNITS; u0 += 256) {
    const int u = u0 + tid;
    const int row = u / C8, c8 = u % C8;
    const int rl = m0 + row;
    if (rl < mcnt) {
      const int grow = ADAPT ? permt[rl] : rl;
      *(short8*)(Cout + (size_t)grow * ldC + n0 + c8 * 8) =
          *(const short8*)(Ct + row * BN + c8 * 8);
    }
  }
}

// ---------------- CSR gather-combine ----------------
template <bool LAST>
__global__ void k_combine(const ushort* __restrict__ Hall, const int* __restrict__ rowptr,
                          const int* __restrict__ epack, const float* __restrict__ invd,
                          const float* __restrict__ bias, void* __restrict__ outp, int N) {
  int v = blockIdx.x * 4 + (threadIdx.x >> 6);
  if (v >= N) return;
  int lane = threadIdx.x & 63;
  int e0 = rowptr[v], e1 = rowptr[v + 1];
  const uint2 s = *(const uint2*)(Hall + (size_t)v * LDH + NREL * D + lane * 4);
  float iv = invd[v];
  const float4 b4 = *(const float4*)(bias + lane * 4);

  float a0 = 0.f, a1 = 0.f, a2 = 0.f, a3 = 0.f;
  int e = e0;
  for (; e + 8 <= e1; e += 8) {
    uint2 u[8];
#pragma unroll
    for (int k = 0; k < 8; ++k) {
      int p = epack[e + k];
      u[k] = *(const uint2*)(Hall + (size_t)(p >> 3) * LDH + (p & 7) * D + lane * 4);
    }
#pragma unroll
    for (int k = 0; k < 8; ++k) {
      a0 += b2f(u[k].x & 0xffffu);
      a1 += __uint_as_float(u[k].x & 0xffff0000u);
      a2 += b2f(u[k].y & 0xffffu);
      a3 += __uint_as_float(u[k].y & 0xffff0000u);
    }
  }
  if (e + 4 <= e1) {
    uint2 u[4];
#pragma unroll
    for (int k = 0; k < 4; ++k) {
      int p = epack[e + k];
      u[k] = *(const uint2*)(Hall + (size_t)(p >> 3) * LDH + (p & 7) * D + lane * 4);
    }
#pragma unroll
    for (int k = 0; k < 4; ++k) {
      a0 += b2f(u[k].x & 0xffffu);
      a1 += __uint_as_float(u[k].x & 0xffff0000u);
      a2 += b2f(u[k].y & 0xffffu);
      a3 += __uint_as_float(u[k].y & 0xffff0000u);
    }
    e += 4;
  }
  for (; e < e1; ++e) {
    int p = epack[e];
    const uint2 u = *(const uint2*)(Hall + (size_t)(p >> 3) * LDH + (p & 7) * D + lane * 4);
    a0 += b2f(u.x & 0xffffu);
    a1 += __uint_as_float(u.x & 0xffff0000u);
    a2 += b2f(u.y & 0xffffu);
    a3 += __uint_as_float(u.y & 0xffff0000u);
  }
  float o0 = fmaxf(fmaf(a0, iv, b2f(s.x & 0xffffu)) + b4.x, 0.f);
  float o1 = fmaxf(fmaf(a1, iv, __uint_as_float(s.x & 0xffff0000u)) + b4.y, 0.f);
  float o2 = fmaxf(fmaf(a2, iv, b2f(s.y & 0xffffu)) + b4.z, 0.f);
  float o3 = fmaxf(fmaf(a3, iv, __uint_as_float(s.y & 0xffff0000u)) + b4.w, 0.f);
  if (LAST) {
    float4 o; o.x = o0; o.y = o1; o.z = o2; o.w = o3;
    ((float4*)outp)[(size_t)v * 64 + lane] = o;
  } else {
    ushort4 o; o.x = f2b(o0); o.y = f2b(o1); o.z = f2b(o2); o.w = f2b(o3);
    ((ushort4*)outp)[(size_t)v * 64 + lane] = o;
  }
}

extern "C" void kernel_launch(void* const* d_in, const int* in_sizes, int n_in,
                              void* d_out, int out_size, void* d_ws, size_t ws_size,
                              hipStream_t stream) {
  const float* X       = (const float*)d_in[0];
  const int*   ntype   = (const int*)d_in[1];
  const int*   eidx    = (const int*)d_in[2];
  const int*   etype   = (const int*)d_in[3];
  const float* adapt_W = (const float*)d_in[5];
  const float* adapt_b = (const float*)d_in[6];
  const float* W_rel   = (const float*)d_in[7];
  const float* W_self  = (const float*)d_in[8];
  const float* b_self  = (const float*)d_in[9];

  const int N = in_sizes[1];
  const int E = in_sizes[3];
  const int* src = eidx;
  const int* dst = eidx + E;

  char* ws = (char*)d_ws;
  size_t o = 0;
  auto alloc = [&](size_t bytes) { void* p = ws + o; o += (bytes + 255) & ~255ull; return p; };

  ushort* Hall  = (ushort*)alloc((size_t)N * LDH * 2);  // 71.7 MB; also aliases Xb
  ushort* Xb    = Hall;                                  // Xb dead before Hall written
  ushort* h     = (ushort*)alloc((size_t)N * D * 2);
  ushort* Wab   = (ushort*)alloc((size_t)NTYPES * D * DIN * 2);
  ushort* Wcat  = (ushort*)alloc((size_t)2 * NSLOT * D * D * 2);
  int*   deg    = (int*)alloc((size_t)N * 4);
  float* inv    = (float*)alloc((size_t)N * 4);
  int*   perm   = (int*)alloc((size_t)N * 4);
  int*   rowptr = (int*)alloc((size_t)(N + 1) * 4);
  int*   cursor = (int*)alloc((size_t)N * 4);
  int*   epack  = (int*)alloc((size_t)E * 4);
  int*   bsum   = (int*)alloc(1024 * 4);
  int*   blockcnt = (int*)alloc((size_t)1024 * NTYPES * 4);
  int*   boffset  = (int*)alloc((size_t)1024 * NTYPES * 4);
  int*   cnt    = (int*)alloc(NTYPES * 4);
  int*   offt   = (int*)alloc(NTYPES * 4);

  const int thr = 256;
  const int nbN = (N + thr - 1) / thr;
  const int nbE = (E + thr - 1) / thr;

  // fused prep: zero deg | X->bf16 | adapt_W->bf16 | pack Wcat  (1 launch)
  const int n4x = N * DIN / 4;
  const int n4w = NTYPES * D * DIN / 4;
  const int nz = nbN;
  const int nx = (n4x + thr - 1) / thr;
  const int nw = (n4w + thr - 1) / thr;
  const int np = 2 * NSLOT * (D * D / 256);
  k_prep_fused<<<nz + nx + nw + np, thr, 0, stream>>>(deg, X, Xb, adapt_W, Wab,
                                                      W_rel, W_self, Wcat,
                                                      N, nz, nx, nw, n4x, n4w);

  // fused: type histogram | degree atomics  (1 launch)
  k_count_fused<<<nbN + nbE, thr, 0, stream>>>(ntype, blockcnt, dst, deg, N, E, nbN);
  k_type_scan<<<1, 512, 0, stream>>>(blockcnt, boffset, cnt, offt, nbN);
  // fused: type scatter | degree block-scan  (1 launch)
  k_scatter_scan<<<2 * nbN, thr, 0, stream>>>(ntype, boffset, perm, deg, rowptr, bsum, N, nbN);
  k_scan_bsum<<<1, 64, 0, stream>>>(bsum, nbN);
  k_scan_add<<<nbN, 256, 0, stream>>>(rowptr, cursor, bsum, deg, inv, N, E);
  k_sortedges<<<nbE, 256, 0, stream>>>(src, dst, etype, cursor, epack, E);

  // adaptation: h = tanh(X @ W_t^T + b_t), bf16 — 64x64 tiles, 1D swizzled grid
  const int mtA = (N + 63) / 64;
  const int nwgA = NTYPES * mtA * (D / 64);
  k_mfma_gemm<64, 64, D / 64, DIN, true, 6><<<nwgA, 256, 0, stream>>>(
      Xb, Wab, adapt_b, perm, cnt, offt, h, N, D);

  // two relational layers — 128x128 tiles, n-fast 1D grid + XCD swizzle
  const int mtL = (N + 127) / 128;
  const int nwgL = mtL * (LDH / 128);
  for (int l = 0; l < 2; ++l) {
    const ushort* Wl = Wcat + (size_t)l * NSLOT * D * D;
    k_mfma_gemm<128, 128, LDH / 128, D, false, 4><<<nwgL, 256, 0, stream>>>(
        h, Wl, nullptr, nullptr, nullptr, nullptr, Hall, N, LDH);
    if (l == 0)
      k_combine<false><<<(N + 3) / 4, 256, 0, stream>>>(Hall, rowptr, epack, inv,
                                                        b_self + (size_t)l * D, h, N);
    else
      k_combine<true><<<(N + 3) / 4, 256, 0, stream>>>(Hall, rowptr, epack, inv,
                                                       b_self + (size_t)l * D, d_out, N);
  }
}

// Round 15
// 187.449 us; speedup vs baseline: 1.2847x; 1.0214x over previous
//
#include <hip/hip_runtime.h>

constexpr int NTYPES = 8;
constexpr int NREL   = 6;
constexpr int NSLOT  = 7;          // 6 relations + self
constexpr int D      = 256;
constexpr int DIN    = 512;
constexpr int LDH    = NSLOT * D;  // 1792

using short8 = __attribute__((ext_vector_type(8))) short;
using f32x4  = __attribute__((ext_vector_type(4))) float;

__device__ __forceinline__ ushort f2b(float f) {  // f32 -> bf16 RNE
  unsigned u = __float_as_uint(f);
  u += 0x7fffu + ((u >> 16) & 1u);
  return (ushort)(u >> 16);
}
__device__ __forceinline__ float b2f(unsigned bits16) {
  return __uint_as_float(bits16 << 16);
}

#define GLOAD_LDS16(g, l)                                              \
  __builtin_amdgcn_global_load_lds(                                    \
      (__attribute__((address_space(1))) void*)(g),                    \
      (__attribute__((address_space(3))) void*)(l), 16, 0, 0)

// ---------------- tiny zero (runtime fillBuffer is ~40us in-graph) ----------------
__global__ void k_zero(int* __restrict__ p, int n) {
  int i = blockIdx.x * blockDim.x + threadIdx.x;
  if (i < n) p[i] = 0;
}

// ------- mega prep: cvtX | cvtW | packWcat | type-hist | degree-atomics -------
// one launch; the two atomic partitions co-schedule with ~100MB of streaming
// conversions, hiding their L2 round-trip latency (round-11/15 lesson).
__global__ void k_prep_mega(const float* __restrict__ X, ushort* __restrict__ Xb,
                            const float* __restrict__ Wa, ushort* __restrict__ Wab,
                            const float* __restrict__ Wrel, const float* __restrict__ Wself,
                            ushort* __restrict__ Wcat,
                            const int* __restrict__ ntype, int* __restrict__ blockcnt,
                            const int* __restrict__ dst, int* __restrict__ deg,
                            int N, int E, int nx, int nw, int np, int nbN,
                            int n4x, int n4w) {
  __shared__ int cnt[NTYPES];
  const int b = blockIdx.x;
  const int tid = threadIdx.x;
  if (b < nx) {                                // X -> bf16
    int i = b * 256 + tid;
    if (i < n4x) {
      float4 v = ((const float4*)X)[i];
      ushort4 o; o.x = f2b(v.x); o.y = f2b(v.y); o.z = f2b(v.z); o.w = f2b(v.w);
      ((ushort4*)Xb)[i] = o;
    }
  } else if (b < nx + nw) {                    // adapt_W -> bf16
    int i = (b - nx) * 256 + tid;
    if (i < n4w) {
      float4 v = ((const float4*)Wa)[i];
      ushort4 o; o.x = f2b(v.x); o.y = f2b(v.y); o.z = f2b(v.z); o.w = f2b(v.w);
      ((ushort4*)Wab)[i] = o;
    }
  } else if (b < nx + nw + np) {               // pack Wcat (transposed, bf16)
    int local = b - nx - nw;                   // 0 .. 2*7*256-1
    int l = local / (NSLOT * 256);
    int s = (local % (NSLOT * 256)) / 256;
    int o = (local % 256) * 256 + tid;         // over D*D
    int e = o >> 8, d = o & 255;
    float v = (s < NREL) ? Wrel[(((size_t)l * NREL + s) * D + d) * D + e]
                         : Wself[((size_t)l * D + d) * D + e];
    Wcat[(((size_t)l * NSLOT + s) * D + e) * D + d] = f2b(v);
  } else if (b < nx + nw + np + nbN) {         // per-block type histogram (ballot)
    const int bb = b - nx - nw - np;
    int i = bb * 256 + tid;
    if (tid < NTYPES) cnt[tid] = 0;
    __syncthreads();
    int t = (i < N) ? ntype[i] : -1;
#pragma unroll
    for (int ty = 0; ty < NTYPES; ++ty) {
      unsigned long long m = __ballot(t == ty);
      if ((tid & 63) == 0 && m) atomicAdd(&cnt[ty], __popcll(m));
    }
    __syncthreads();
    if (tid < NTYPES) blockcnt[bb * NTYPES + tid] = cnt[tid];
  } else {                                     // degree atomics (deg zeroed in L0)
    int e = (b - nx - nw - np - nbN) * 256 + tid;
    if (e < E) atomicAdd(&deg[dst[e]], 1);
  }
}

// ---- fused scans: block0 = wave-parallel type scan; blocks 1.. = 512-wide
// degree block-scan chunks (Hillis-Steele in LDS), emitting bsum partials ----
__global__ __launch_bounds__(512)
void k_scan2(const int* __restrict__ blockcnt, int* __restrict__ boffset,
             int* __restrict__ cnt, int* __restrict__ offt, int nbN,
             const int* __restrict__ deg, int* __restrict__ rowptr,
             int* __restrict__ bsum, int N) {
  if (blockIdx.x == 0) {
    __shared__ int tot[NTYPES];
    __shared__ int base[NTYPES];
    const int w = threadIdx.x >> 6;   // type
    const int l = threadIdx.x & 63;
    int v0 = (l < nbN) ? blockcnt[l * NTYPES + w] : 0;
    int v1 = (64 + l < nbN) ? blockcnt[(64 + l) * NTYPES + w] : 0;
    int s0 = v0;
#pragma unroll
    for (int o = 1; o < 64; o <<= 1) { int t = __shfl_up(s0, o); if (l >= o) s0 += t; }
    int total0 = __shfl(s0, 63);
    int s1 = v1;
#pragma unroll
    for (int o = 1; o < 64; o <<= 1) { int t = __shfl_up(s1, o); if (l >= o) s1 += t; }
    s1 += total0;
    int totalw = __shfl(s1, 63);
    if (l == 0) { tot[w] = totalw; cnt[w] = totalw; }
    __syncthreads();
    if (threadIdx.x == 0) {
      int s = 0;
      for (int ty = 0; ty < NTYPES; ++ty) { base[ty] = s; offt[ty] = s; s += tot[ty]; }
    }
    __syncthreads();
    const int bs = base[w];
    if (l < nbN) boffset[l * NTYPES + w] = bs + s0 - v0;            // exclusive
    if (64 + l < nbN) boffset[(64 + l) * NTYPES + w] = bs + s1 - v1;
  } else {
    __shared__ int sm[512];
    const int bb = blockIdx.x - 1;
    const int t = threadIdx.x;
    int i = bb * 512 + t;
    int v = (i < N) ? deg[i] : 0;
    sm[t] = v;
    __syncthreads();
    for (int o = 1; o < 512; o <<= 1) {
      int x = (t >= o) ? sm[t - o] : 0;
      __syncthreads();
      sm[t] += x;
      __syncthreads();
    }
    if (i < N) rowptr[i] = sm[t] - v;   // exclusive within 512-chunk
    if (t == 511) bsum[bb] = sm[511];
  }
}

// ---- fused: type scatter (perm) blocks | bsum exclusive scan (last block) ----
__global__ void k_scatter_bsum(const int* __restrict__ ntype, const int* __restrict__ boffset,
                               int* __restrict__ perm, int N, int nbN,
                               int* __restrict__ bsum, int nbs) {
  __shared__ int cur[NTYPES];
  const int b = blockIdx.x;
  if (b < nbN) {
    int i = b * 256 + threadIdx.x;
    if (threadIdx.x < NTYPES) cur[threadIdx.x] = boffset[b * NTYPES + threadIdx.x];
    __syncthreads();
    int t = (i < N) ? ntype[i] : -1;
    int lane = threadIdx.x & 63;
#pragma unroll
    for (int ty = 0; ty < NTYPES; ++ty) {
      unsigned long long m = __ballot(t == ty);
      if (m) {
        int wbase = 0;
        if (lane == 0) wbase = atomicAdd(&cur[ty], __popcll(m));
        wbase = __shfl(wbase, 0);
        if (t == ty) {
          int rank = __popcll(m & ((1ull << lane) - 1ull));
          perm[wbase + rank] = i;
        }
      }
    }
  } else if (threadIdx.x < 64) {            // single-wave exclusive scan, nbs<=64
    const int l = threadIdx.x;
    int v0 = (l < nbs) ? bsum[l] : 0;
    int s0 = v0;
#pragma unroll
    for (int o = 1; o < 64; o <<= 1) { int t = __shfl_up(s0, o); if (l >= o) s0 += t; }
    if (l < nbs) bsum[l] = s0 - v0;
  }
}

// adds 512-chunk offsets AND computes cursor + inv_deg in the same pass
__global__ void k_scan_add(int* __restrict__ rowptr, int* __restrict__ cursor,
                           const int* __restrict__ bsum, const int* __restrict__ deg,
                           float* __restrict__ inv, int N, int E) {
  int i = blockIdx.x * 256 + threadIdx.x;
  if (i < N) {
    int r = rowptr[i] + bsum[i >> 9];
    rowptr[i] = r;
    cursor[i] = r;
    inv[i] = 1.0f / fmaxf((float)deg[i], 1.0f);
  }
  if (i == 0) rowptr[N] = E;
}

// ---------------- MFMA GEMM: T4 counted-vmcnt 3-buffer pipeline ----------------
// C[m][n] = sum_k A[m][k] * B[n][k]   (B stored row-per-output-col, k-contiguous)
// BMxBN tile, 4 waves (2x2), BK=32, bf16 in / f32 acc / bf16 out.
// Counted s_waitcnt keeps the newest stage in flight across the raw s_barrier;
// sched_barrier(0) right after each s_barrier blocks STAGE/ds_read hoisting
// (rounds 6-7 race). Epilogue guarded by real __syncthreads (IR fence).
// SORT: blocks with blockIdx >= nwg instead run the edge counting-sort — the
// ~12us of E atomics hides under the adapt GEMM's MFMA work (round-15 change).
template <int BM, int BN, int NTN, int KDIM, bool ADAPT, bool SORT, int OCC>
__global__ __launch_bounds__(256, OCC)
void k_mfma_gemm(const ushort* __restrict__ A, const ushort* __restrict__ B,
                 const float* __restrict__ bias,
                 const int* __restrict__ perm, const int* __restrict__ cnt,
                 const int* __restrict__ off,
                 ushort* __restrict__ Cout, int N, int ldC, int nwg,
                 const int* __restrict__ s_src, const int* __restrict__ s_dst,
                 const int* __restrict__ s_et, int* __restrict__ s_cursor,
                 int* __restrict__ s_epack, int s_E) {
  if (SORT && (int)blockIdx.x >= nwg) {       // edge counting-sort partition
    int e = ((int)blockIdx.x - nwg) * 256 + threadIdx.x;
    if (e < s_E) {
      int pos = atomicAdd(&s_cursor[s_dst[e]], 1);
      s_epack[pos] = (s_src[e] << 3) | s_et[e];
    }
    return;
  }

  // bijective XCD swizzle over the GEMM sub-grid
  const int qq = nwg >> 3, rr = nwg & 7;
  const int xcd = blockIdx.x & 7, idx = blockIdx.x >> 3;
  const int wgid = (xcd < rr ? xcd * (qq + 1) : rr * (qq + 1) + (xcd - rr) * qq) + idx;

  int mcnt = N, mtile, ntile;
  const int* permt = nullptr;
  const ushort* Bt = B;
  const float* biast = bias;
  if (ADAPT) {
    const int mt = nwg / (NTYPES * NTN);
    const int t = wgid / (mt * NTN);
    const int rem = wgid % (mt * NTN);
    mtile = rem / NTN;
    ntile = rem % NTN;
    mcnt = cnt[t];
    permt = perm + off[t];
    Bt = B + (size_t)t * D * KDIM;
    biast = bias + t * D;
  } else {
    mtile = wgid / NTN;
    ntile = wgid % NTN;
  }
  const int m0 = mtile * BM;
  if (m0 >= mcnt) return;
  const int n0 = ntile * BN;

  __shared__ ushort SM[3][2][BM * 32];   // [buf][A=0/B=1][row*32+k]
  static_assert(BM * BN <= 3 * 2 * BM * 32, "C tile must fit in staging LDS");

  const int tid  = threadIdx.x;
  const int lane = tid & 63;
  const int w    = tid >> 6;
  constexpr int FR = BM / 32;
  constexpr int FC = BN / 32;
  const int wr   = (w >> 1) * (BM / 2);
  const int wc   = (w & 1) * (BN / 2);

  // staging: (BM/16) x 1KB calls per matrix; wave w does calls {w, w+4, ...}.
  // XOR swizzle on GLOBAL source slot (LDS dest linear), undone at ds_read.
  constexpr int PW = BM / 16 / 4;        // calls per wave per matrix (1 or 2)
  const ushort* gA[PW];
  const ushort* gB[PW];
  int lo[PW];
#pragma unroll
  for (int u = 0; u < PW; ++u) {
    const int c  = w + u * 4;
    const int r  = c * 16 + (lane >> 2);
    const int sl = (lane & 3) ^ ((r >> 1) & 3);
    int ga;
    if (ADAPT) ga = permt[min(m0 + r, mcnt - 1)];
    else       ga = min(m0 + r, N - 1);
    gA[u] = A + (size_t)ga * KDIM + sl * 8;
    gB[u] = Bt + (size_t)(n0 + r) * KDIM + sl * 8;
    lo[u] = c * 512;
  }

  auto STAGE = [&](int k0, int buf) {
#pragma unroll
    for (int u = 0; u < PW; ++u) {
      GLOAD_LDS16(gA[u] + k0, &SM[buf][0][lo[u]]);
      GLOAD_LDS16(gB[u] + k0, &SM[buf][1][lo[u]]);
    }
  };
  // wait until only the newest stage (PW*2 loads) may be outstanding
  auto WAIT_LPS = [&]() {
    if constexpr (PW == 1) asm volatile("s_waitcnt vmcnt(2)" ::: "memory");
    else                   asm volatile("s_waitcnt vmcnt(4)" ::: "memory");
  };

  f32x4 acc[FR][FC] = {};
  const int r15 = lane & 15;
  const int g   = lane >> 4;
  const int gsw = g ^ ((r15 >> 1) & 3);

  auto COMPUTE = [&](int buf) {
    short8 af[FR], bf[FC];
#pragma unroll
    for (int i = 0; i < FR; ++i)
      af[i] = *(const short8*)(&SM[buf][0][(wr + i * 16 + r15) * 32 + gsw * 8]);
#pragma unroll
    for (int j = 0; j < FC; ++j)
      bf[j] = *(const short8*)(&SM[buf][1][(wc + j * 16 + r15) * 32 + gsw * 8]);
#pragma unroll
    for (int i = 0; i < FR; ++i)
#pragma unroll
      for (int j = 0; j < FC; ++j)
        acc[i][j] = __builtin_amdgcn_mfma_f32_16x16x32_bf16(af[i], bf[j], acc[i][j], 0, 0, 0);
  };

  constexpr int NT = KDIM / 32;
  static_assert(NT >= 3, "pipeline needs NT >= 3");

  // prologue: two stages in flight
  STAGE(0, 0);
  STAGE(32, 1);

#pragma unroll
  for (int kt = 0; kt < NT - 1; ++kt) {
    WAIT_LPS();                               // stage(kt) landed; stage(kt+1) in flight
    __builtin_amdgcn_s_barrier();             // all waves' stage(kt) visible
    __builtin_amdgcn_sched_barrier(0);        // nothing hoists above the barrier
    COMPUTE(kt % 3);
    if (kt + 2 < NT) STAGE((kt + 2) * 32, (kt + 2) % 3);
  }
  asm volatile("s_waitcnt vmcnt(0)" ::: "memory");
  __builtin_amdgcn_s_barrier();
  __builtin_amdgcn_sched_barrier(0);
  COMPUTE((NT - 1) % 3);

  // ---- epilogue: C/D layout (m89): col = lane&15, row = (lane>>4)*4 + reg ----
  __syncthreads();   // IR fence + barrier: Ct writes can't overlap final reads
  ushort* Ct = (ushort*)SM;
#pragma unroll
  for (int i = 0; i < FR; ++i) {
#pragma unroll
    for (int q4 = 0; q4 < 4; ++q4) {
      const int row = wr + i * 16 + (lane >> 4) * 4 + q4;
#pragma unroll
      for (int j = 0; j < FC; ++j) {
        const int col = wc + j * 16 + r15;
        float v = acc[i][j][q4];
        if (ADAPT) v = tanhf(v + biast[n0 + col]);
        Ct[row * BN + col] = f2b(v);
      }
    }
  }
  __syncthreads();
  constexpr int C8 = BN / 8;
  constexpr int UNITS = BM * C8;
#pragma unroll
  for (int u0 = 0; u0 < UNITS; u0 += 256) {
    const int u = u0 + tid;
    const int row = u / C8, c8 = u % C8;
    const int rl = m0 + row;
    if (rl < mcnt) {
      const int grow = ADAPT ? permt[rl] : rl;
      *(short8*)(Cout + (size_t)grow * ldC + n0 + c8 * 8) =
          *(const short8*)(Ct + row * BN + c8 * 8);
    }
  }
}

// ---------------- CSR gather-combine ----------------
template <bool LAST>
__global__ void k_combine(const ushort* __restrict__ Hall, const int* __restrict__ rowptr,
                          const int* __restrict__ epack, const float* __restrict__ invd,
                          const float* __restrict__ bias, void* __restrict__ outp, int N) {
  int v = blockIdx.x * 4 + (threadIdx.x >> 6);
  if (v >= N) return;
  int lane = threadIdx.x & 63;
  int e0 = rowptr[v], e1 = rowptr[v + 1];
  const uint2 s = *(const uint2*)(Hall + (size_t)v * LDH + NREL * D + lane * 4);
  float iv = invd[v];
  const float4 b4 = *(const float4*)(bias + lane * 4);

  float a0 = 0.f, a1 = 0.f, a2 = 0.f, a3 = 0.f;
  int e = e0;
  for (; e + 8 <= e1; e += 8) {
    uint2 u[8];
#pragma unroll
    for (int k = 0; k < 8; ++k) {
      int p = epack[e + k];
      u[k] = *(const uint2*)(Hall + (size_t)(p >> 3) * LDH + (p & 7) * D + lane * 4);
    }
#pragma unroll
    for (int k = 0; k < 8; ++k) {
      a0 += b2f(u[k].x & 0xffffu);
      a1 += __uint_as_float(u[k].x & 0xffff0000u);
      a2 += b2f(u[k].y & 0xffffu);
      a3 += __uint_as_float(u[k].y & 0xffff0000u);
    }
  }
  if (e + 4 <= e1) {
    uint2 u[4];
#pragma unroll
    for (int k = 0; k < 4; ++k) {
      int p = epack[e + k];
      u[k] = *(const uint2*)(Hall + (size_t)(p >> 3) * LDH + (p & 7) * D + lane * 4);
    }
#pragma unroll
    for (int k = 0; k < 4; ++k) {
      a0 += b2f(u[k].x & 0xffffu);
      a1 += __uint_as_float(u[k].x & 0xffff0000u);
      a2 += b2f(u[k].y & 0xffffu);
      a3 += __uint_as_float(u[k].y & 0xffff0000u);
    }
    e += 4;
  }
  for (; e < e1; ++e) {
    int p = epack[e];
    const uint2 u = *(const uint2*)(Hall + (size_t)(p >> 3) * LDH + (p & 7) * D + lane * 4);
    a0 += b2f(u.x & 0xffffu);
    a1 += __uint_as_float(u.x & 0xffff0000u);
    a2 += b2f(u.y & 0xffffu);
    a3 += __uint_as_float(u.y & 0xffff0000u);
  }
  float o0 = fmaxf(fmaf(a0, iv, b2f(s.x & 0xffffu)) + b4.x, 0.f);
  float o1 = fmaxf(fmaf(a1, iv, __uint_as_float(s.x & 0xffff0000u)) + b4.y, 0.f);
  float o2 = fmaxf(fmaf(a2, iv, b2f(s.y & 0xffffu)) + b4.z, 0.f);
  float o3 = fmaxf(fmaf(a3, iv, __uint_as_float(s.y & 0xffff0000u)) + b4.w, 0.f);
  if (LAST) {
    float4 o; o.x = o0; o.y = o1; o.z = o2; o.w = o3;
    ((float4*)outp)[(size_t)v * 64 + lane] = o;
  } else {
    ushort4 o; o.x = f2b(o0); o.y = f2b(o1); o.z = f2b(o2); o.w = f2b(o3);
    ((ushort4*)outp)[(size_t)v * 64 + lane] = o;
  }
}

extern "C" void kernel_launch(void* const* d_in, const int* in_sizes, int n_in,
                              void* d_out, int out_size, void* d_ws, size_t ws_size,
                              hipStream_t stream) {
  const float* X       = (const float*)d_in[0];
  const int*   ntype   = (const int*)d_in[1];
  const int*   eidx    = (const int*)d_in[2];
  const int*   etype   = (const int*)d_in[3];
  const float* adapt_W = (const float*)d_in[5];
  const float* adapt_b = (const float*)d_in[6];
  const float* W_rel   = (const float*)d_in[7];
  const float* W_self  = (const float*)d_in[8];
  const float* b_self  = (const float*)d_in[9];

  const int N = in_sizes[1];
  const int E = in_sizes[3];
  const int* src = eidx;
  const int* dst = eidx + E;

  char* ws = (char*)d_ws;
  size_t o = 0;
  auto alloc = [&](size_t bytes) { void* p = ws + o; o += (bytes + 255) & ~255ull; return p; };

  ushort* Hall  = (ushort*)alloc((size_t)N * LDH * 2);  // 71.7 MB; also aliases Xb
  ushort* Xb    = Hall;                                  // Xb dead before Hall written
  ushort* h     = (ushort*)alloc((size_t)N * D * 2);
  ushort* Wab   = (ushort*)alloc((size_t)NTYPES * D * DIN * 2);
  ushort* Wcat  = (ushort*)alloc((size_t)2 * NSLOT * D * D * 2);
  int*   deg    = (int*)alloc((size_t)N * 4);
  float* inv    = (float*)alloc((size_t)N * 4);
  int*   perm   = (int*)alloc((size_t)N * 4);
  int*   rowptr = (int*)alloc((size_t)(N + 1) * 4);
  int*   cursor = (int*)alloc((size_t)N * 4);
  int*   epack  = (int*)alloc((size_t)E * 4);
  int*   bsum   = (int*)alloc(1024 * 4);
  int*   blockcnt = (int*)alloc((size_t)1024 * NTYPES * 4);
  int*   boffset  = (int*)alloc((size_t)1024 * NTYPES * 4);
  int*   cnt    = (int*)alloc(NTYPES * 4);
  int*   offt   = (int*)alloc(NTYPES * 4);

  const int thr = 256;
  const int nbN = (N + thr - 1) / thr;            // 256-chunks of nodes
  const int nbE = (E + thr - 1) / thr;            // 256-chunks of edges
  const int nbN512 = (N + 511) / 512;             // 512-chunks for degree scan

  // L0: zero deg
  k_zero<<<nbN, thr, 0, stream>>>(deg, N);

  // L1: mega prep — cvtX | cvtW | packWcat | type-hist | degree (one launch)
  const int n4x = N * DIN / 4;
  const int n4w = NTYPES * D * DIN / 4;
  const int nx = (n4x + thr - 1) / thr;
  const int nw = (n4w + thr - 1) / thr;
  const int np = 2 * NSLOT * (D * D / 256);
  k_prep_mega<<<nx + nw + np + nbN + nbE, thr, 0, stream>>>(
      X, Xb, adapt_W, Wab, W_rel, W_self, Wcat, ntype, blockcnt, dst, deg,
      N, E, nx, nw, np, nbN, n4x, n4w);

  // L2: fused scans — type_scan (block 0) | 512-wide degree chunk scans
  k_scan2<<<1 + nbN512, 512, 0, stream>>>(blockcnt, boffset, cnt, offt, nbN,
                                          deg, rowptr, bsum, N);

  // L3: fused — type scatter (perm) | bsum exclusive scan (last block)
  k_scatter_bsum<<<nbN + 1, thr, 0, stream>>>(ntype, boffset, perm, N, nbN, bsum, nbN512);

  // L4: finalize rowptr/cursor/inv
  k_scan_add<<<nbN, thr, 0, stream>>>(rowptr, cursor, bsum, deg, inv, N, E);

  // L5: adaptation GEMM | edge counting-sort (fused — sort atomics hide under MFMA)
  const int mtA = (N + 63) / 64;
  const int nwgA = NTYPES * mtA * (D / 64);
  k_mfma_gemm<64, 64, D / 64, DIN, true, true, 6><<<nwgA + nbE, 256, 0, stream>>>(
      Xb, Wab, adapt_b, perm, cnt, offt, h, N, D, nwgA,
      src, dst, etype, cursor, epack, E);

  // L6-L9: two relational layers — 128x128 GEMM + CSR combine
  const int mtL = (N + 127) / 128;
  const int nwgL = mtL * (LDH / 128);
  for (int l = 0; l < 2; ++l) {
    const ushort* Wl = Wcat + (size_t)l * NSLOT * D * D;
    k_mfma_gemm<128, 128, LDH / 128, D, false, false, 4><<<nwgL, 256, 0, stream>>>(
        h, Wl, nullptr, nullptr, nullptr, nullptr, Hall, N, LDH, nwgL,
        nullptr, nullptr, nullptr, nullptr, nullptr, 0);
    if (l == 0)
      k_combine<false><<<(N + 3) / 4, 256, 0, stream>>>(Hall, rowptr, epack, inv,
                                                        b_self + (size_t)l * D, h, N);
    else
      k_combine<true><<<(N + 3) / 4, 256, 0, stream>>>(Hall, rowptr, epack, inv,
                                                       b_self + (size_t)l * D, d_out, N);
  }
}

// Round 16
// 187.289 us; speedup vs baseline: 1.2858x; 1.0009x over previous
//
#include <hip/hip_runtime.h>

constexpr int NTYPES = 8;
constexpr int NREL   = 6;
constexpr int NSLOT  = 7;          // 6 relations + self
constexpr int D      = 256;
constexpr int DIN    = 512;
constexpr int LDH    = NSLOT * D;  // 1792

using short8 = __attribute__((ext_vector_type(8))) short;
using f32x4  = __attribute__((ext_vector_type(4))) float;

__device__ __forceinline__ ushort f2b(float f) {  // f32 -> bf16 RNE
  unsigned u = __float_as_uint(f);
  u += 0x7fffu + ((u >> 16) & 1u);
  return (ushort)(u >> 16);
}
__device__ __forceinline__ float b2f(unsigned bits16) {
  return __uint_as_float(bits16 << 16);
}

#define GLOAD_LDS16(g, l)                                              \
  __builtin_amdgcn_global_load_lds(                                    \
      (__attribute__((address_space(1))) void*)(g),                    \
      (__attribute__((address_space(3))) void*)(l), 16, 0, 0)

// ---------------- tiny zero (runtime fillBuffer is ~40us in-graph) ----------------
__global__ void k_zero(int* __restrict__ p, int n) {
  int i = blockIdx.x * blockDim.x + threadIdx.x;
  if (i < n) p[i] = 0;
}

// ------- mega prep: cvtX | cvtW | packWcat | type-hist | degree-atomics -------
// one launch; the two atomic partitions co-schedule with ~100MB of streaming
// conversions, hiding their L2 round-trip latency (round-11/15 lesson).
__global__ void k_prep_mega(const float* __restrict__ X, ushort* __restrict__ Xb,
                            const float* __restrict__ Wa, ushort* __restrict__ Wab,
                            const float* __restrict__ Wrel, const float* __restrict__ Wself,
                            ushort* __restrict__ Wcat,
                            const int* __restrict__ ntype, int* __restrict__ blockcnt,
                            const int* __restrict__ dst, int* __restrict__ deg,
                            int N, int E, int nx, int nw, int np, int nbN,
                            int n4x, int n4w) {
  __shared__ int cnt[NTYPES];
  const int b = blockIdx.x;
  const int tid = threadIdx.x;
  if (b < nx) {                                // X -> bf16
    int i = b * 256 + tid;
    if (i < n4x) {
      float4 v = ((const float4*)X)[i];
      ushort4 o; o.x = f2b(v.x); o.y = f2b(v.y); o.z = f2b(v.z); o.w = f2b(v.w);
      ((ushort4*)Xb)[i] = o;
    }
  } else if (b < nx + nw) {                    // adapt_W -> bf16
    int i = (b - nx) * 256 + tid;
    if (i < n4w) {
      float4 v = ((const float4*)Wa)[i];
      ushort4 o; o.x = f2b(v.x); o.y = f2b(v.y); o.z = f2b(v.z); o.w = f2b(v.w);
      ((ushort4*)Wab)[i] = o;
    }
  } else if (b < nx + nw + np) {               // pack Wcat (transposed, bf16)
    int local = b - nx - nw;                   // 0 .. 2*7*256-1
    int l = local / (NSLOT * 256);
    int s = (local % (NSLOT * 256)) / 256;
    int o = (local % 256) * 256 + tid;         // over D*D
    int e = o >> 8, d = o & 255;
    float v = (s < NREL) ? Wrel[(((size_t)l * NREL + s) * D + d) * D + e]
                         : Wself[((size_t)l * D + d) * D + e];
    Wcat[(((size_t)l * NSLOT + s) * D + e) * D + d] = f2b(v);
  } else if (b < nx + nw + np + nbN) {         // per-block type histogram (ballot)
    const int bb = b - nx - nw - np;
    int i = bb * 256 + tid;
    if (tid < NTYPES) cnt[tid] = 0;
    __syncthreads();
    int t = (i < N) ? ntype[i] : -1;
#pragma unroll
    for (int ty = 0; ty < NTYPES; ++ty) {
      unsigned long long m = __ballot(t == ty);
      if ((tid & 63) == 0 && m) atomicAdd(&cnt[ty], __popcll(m));
    }
    __syncthreads();
    if (tid < NTYPES) blockcnt[bb * NTYPES + tid] = cnt[tid];
  } else {                                     // degree atomics (deg zeroed in L0)
    int e = (b - nx - nw - np - nbN) * 256 + tid;
    if (e < E) atomicAdd(&deg[dst[e]], 1);
  }
}

// ---- fused scans: block0 = wave-parallel type scan; blocks 1.. = 512-wide
// degree block-scan chunks (Hillis-Steele in LDS), emitting bsum partials ----
__global__ __launch_bounds__(512)
void k_scan2(const int* __restrict__ blockcnt, int* __restrict__ boffset,
             int* __restrict__ cnt, int* __restrict__ offt, int nbN,
             const int* __restrict__ deg, int* __restrict__ rowptr,
             int* __restrict__ bsum, int N) {
  if (blockIdx.x == 0) {
    __shared__ int tot[NTYPES];
    __shared__ int base[NTYPES];
    const int w = threadIdx.x >> 6;   // type
    const int l = threadIdx.x & 63;
    int v0 = (l < nbN) ? blockcnt[l * NTYPES + w] : 0;
    int v1 = (64 + l < nbN) ? blockcnt[(64 + l) * NTYPES + w] : 0;
    int s0 = v0;
#pragma unroll
    for (int o = 1; o < 64; o <<= 1) { int t = __shfl_up(s0, o); if (l >= o) s0 += t; }
    int total0 = __shfl(s0, 63);
    int s1 = v1;
#pragma unroll
    for (int o = 1; o < 64; o <<= 1) { int t = __shfl_up(s1, o); if (l >= o) s1 += t; }
    s1 += total0;
    int totalw = __shfl(s1, 63);
    if (l == 0) { tot[w] = totalw; cnt[w] = totalw; }
    __syncthreads();
    if (threadIdx.x == 0) {
      int s = 0;
      for (int ty = 0; ty < NTYPES; ++ty) { base[ty] = s; offt[ty] = s; s += tot[ty]; }
    }
    __syncthreads();
    const int bs = base[w];
    if (l < nbN) boffset[l * NTYPES + w] = bs + s0 - v0;            // exclusive
    if (64 + l < nbN) boffset[(64 + l) * NTYPES + w] = bs + s1 - v1;
  } else {
    __shared__ int sm[512];
    const int bb = blockIdx.x - 1;
    const int t = threadIdx.x;
    int i = bb * 512 + t;
    int v = (i < N) ? deg[i] : 0;
    sm[t] = v;
    __syncthreads();
    for (int o = 1; o < 512; o <<= 1) {
      int x = (t >= o) ? sm[t - o] : 0;
      __syncthreads();
      sm[t] += x;
      __syncthreads();
    }
    if (i < N) rowptr[i] = sm[t] - v;   // exclusive within 512-chunk
    if (t == 511) bsum[bb] = sm[511];
  }
}

// ---- fused: type scatter (perm) blocks | bsum exclusive scan (last block) ----
__global__ void k_scatter_bsum(const int* __restrict__ ntype, const int* __restrict__ boffset,
                               int* __restrict__ perm, int N, int nbN,
                               int* __restrict__ bsum, int nbs) {
  __shared__ int cur[NTYPES];
  const int b = blockIdx.x;
  if (b < nbN) {
    int i = b * 256 + threadIdx.x;
    if (threadIdx.x < NTYPES) cur[threadIdx.x] = boffset[b * NTYPES + threadIdx.x];
    __syncthreads();
    int t = (i < N) ? ntype[i] : -1;
    int lane = threadIdx.x & 63;
#pragma unroll
    for (int ty = 0; ty < NTYPES; ++ty) {
      unsigned long long m = __ballot(t == ty);
      if (m) {
        int wbase = 0;
        if (lane == 0) wbase = atomicAdd(&cur[ty], __popcll(m));
        wbase = __shfl(wbase, 0);
        if (t == ty) {
          int rank = __popcll(m & ((1ull << lane) - 1ull));
          perm[wbase + rank] = i;
        }
      }
    }
  } else if (threadIdx.x < 64) {            // single-wave exclusive scan, nbs<=64
    const int l = threadIdx.x;
    int v0 = (l < nbs) ? bsum[l] : 0;
    int s0 = v0;
#pragma unroll
    for (int o = 1; o < 64; o <<= 1) { int t = __shfl_up(s0, o); if (l >= o) s0 += t; }
    if (l < nbs) bsum[l] = s0 - v0;
  }
}

// adds 512-chunk offsets AND computes cursor + inv_deg in the same pass
__global__ void k_scan_add(int* __restrict__ rowptr, int* __restrict__ cursor,
                           const int* __restrict__ bsum, const int* __restrict__ deg,
                           float* __restrict__ inv, int N, int E) {
  int i = blockIdx.x * 256 + threadIdx.x;
  if (i < N) {
    int r = rowptr[i] + bsum[i >> 9];
    rowptr[i] = r;
    cursor[i] = r;
    inv[i] = 1.0f / fmaxf((float)deg[i], 1.0f);
  }
  if (i == 0) rowptr[N] = E;
}

// ---------------- MFMA GEMM: T4 counted-vmcnt 3-buffer pipeline ----------------
// C[m][n] = sum_k A[m][k] * B[n][k]   (B stored row-per-output-col, k-contiguous)
// BMxBN tile, 4 waves (2x2), BK=32, bf16 in / f32 acc / bf16 out.
// Counted s_waitcnt keeps the newest stage in flight across the raw s_barrier;
// sched_barrier(0) right after each s_barrier blocks STAGE/ds_read hoisting
// (rounds 6-7 race). Epilogue guarded by real __syncthreads (IR fence).
// SORT: blocks with blockIdx >= nwg instead run the edge counting-sort — the
// ~12us of E atomics hides under the adapt GEMM's MFMA work (round-15 change).
template <int BM, int BN, int NTN, int KDIM, bool ADAPT, bool SORT, int OCC>
__global__ __launch_bounds__(256, OCC)
void k_mfma_gemm(const ushort* __restrict__ A, const ushort* __restrict__ B,
                 const float* __restrict__ bias,
                 const int* __restrict__ perm, const int* __restrict__ cnt,
                 const int* __restrict__ off,
                 ushort* __restrict__ Cout, int N, int ldC, int nwg,
                 const int* __restrict__ s_src, const int* __restrict__ s_dst,
                 const int* __restrict__ s_et, int* __restrict__ s_cursor,
                 int* __restrict__ s_epack, int s_E) {
  if (SORT && (int)blockIdx.x >= nwg) {       // edge counting-sort partition
    int e = ((int)blockIdx.x - nwg) * 256 + threadIdx.x;
    if (e < s_E) {
      int pos = atomicAdd(&s_cursor[s_dst[e]], 1);
      s_epack[pos] = (s_src[e] << 3) | s_et[e];
    }
    return;
  }

  // bijective XCD swizzle over the GEMM sub-grid
  const int qq = nwg >> 3, rr = nwg & 7;
  const int xcd = blockIdx.x & 7, idx = blockIdx.x >> 3;
  const int wgid = (xcd < rr ? xcd * (qq + 1) : rr * (qq + 1) + (xcd - rr) * qq) + idx;

  int mcnt = N, mtile, ntile;
  const int* permt = nullptr;
  const ushort* Bt = B;
  const float* biast = bias;
  if (ADAPT) {
    const int mt = nwg / (NTYPES * NTN);
    const int t = wgid / (mt * NTN);
    const int rem = wgid % (mt * NTN);
    mtile = rem / NTN;
    ntile = rem % NTN;
    mcnt = cnt[t];
    permt = perm + off[t];
    Bt = B + (size_t)t * D * KDIM;
    biast = bias + t * D;
  } else {
    mtile = wgid / NTN;
    ntile = wgid % NTN;
  }
  const int m0 = mtile * BM;
  if (m0 >= mcnt) return;
  const int n0 = ntile * BN;

  __shared__ ushort SM[3][2][BM * 32];   // [buf][A=0/B=1][row*32+k]
  static_assert(BM * BN <= 3 * 2 * BM * 32, "C tile must fit in staging LDS");

  const int tid  = threadIdx.x;
  const int lane = tid & 63;
  const int w    = tid >> 6;
  constexpr int FR = BM / 32;
  constexpr int FC = BN / 32;
  const int wr   = (w >> 1) * (BM / 2);
  const int wc   = (w & 1) * (BN / 2);

  // staging: (BM/16) x 1KB calls per matrix; wave w does calls {w, w+4, ...}.
  // XOR swizzle on GLOBAL source slot (LDS dest linear), undone at ds_read.
  constexpr int PW = BM / 16 / 4;        // calls per wave per matrix (1 or 2)
  const ushort* gA[PW];
  const ushort* gB[PW];
  int lo[PW];
#pragma unroll
  for (int u = 0; u < PW; ++u) {
    const int c  = w + u * 4;
    const int r  = c * 16 + (lane >> 2);
    const int sl = (lane & 3) ^ ((r >> 1) & 3);
    int ga;
    if (ADAPT) ga = permt[min(m0 + r, mcnt - 1)];
    else       ga = min(m0 + r, N - 1);
    gA[u] = A + (size_t)ga * KDIM + sl * 8;
    gB[u] = Bt + (size_t)(n0 + r) * KDIM + sl * 8;
    lo[u] = c * 512;
  }

  auto STAGE = [&](int k0, int buf) {
#pragma unroll
    for (int u = 0; u < PW; ++u) {
      GLOAD_LDS16(gA[u] + k0, &SM[buf][0][lo[u]]);
      GLOAD_LDS16(gB[u] + k0, &SM[buf][1][lo[u]]);
    }
  };
  // wait until only the newest stage (PW*2 loads) may be outstanding
  auto WAIT_LPS = [&]() {
    if constexpr (PW == 1) asm volatile("s_waitcnt vmcnt(2)" ::: "memory");
    else                   asm volatile("s_waitcnt vmcnt(4)" ::: "memory");
  };

  f32x4 acc[FR][FC] = {};
  const int r15 = lane & 15;
  const int g   = lane >> 4;
  const int gsw = g ^ ((r15 >> 1) & 3);

  auto COMPUTE = [&](int buf) {
    short8 af[FR], bf[FC];
#pragma unroll
    for (int i = 0; i < FR; ++i)
      af[i] = *(const short8*)(&SM[buf][0][(wr + i * 16 + r15) * 32 + gsw * 8]);
#pragma unroll
    for (int j = 0; j < FC; ++j)
      bf[j] = *(const short8*)(&SM[buf][1][(wc + j * 16 + r15) * 32 + gsw * 8]);
#pragma unroll
    for (int i = 0; i < FR; ++i)
#pragma unroll
      for (int j = 0; j < FC; ++j)
        acc[i][j] = __builtin_amdgcn_mfma_f32_16x16x32_bf16(af[i], bf[j], acc[i][j], 0, 0, 0);
  };

  constexpr int NT = KDIM / 32;
  static_assert(NT >= 3, "pipeline needs NT >= 3");

  // prologue: two stages in flight
  STAGE(0, 0);
  STAGE(32, 1);

#pragma unroll
  for (int kt = 0; kt < NT - 1; ++kt) {
    WAIT_LPS();                               // stage(kt) landed; stage(kt+1) in flight
    __builtin_amdgcn_s_barrier();             // all waves' stage(kt) visible
    __builtin_amdgcn_sched_barrier(0);        // nothing hoists above the barrier
    COMPUTE(kt % 3);
    if (kt + 2 < NT) STAGE((kt + 2) * 32, (kt + 2) % 3);
  }
  asm volatile("s_waitcnt vmcnt(0)" ::: "memory");
  __builtin_amdgcn_s_barrier();
  __builtin_amdgcn_sched_barrier(0);
  COMPUTE((NT - 1) % 3);

  // ---- epilogue: C/D layout (m89): col = lane&15, row = (lane>>4)*4 + reg ----
  __syncthreads();   // IR fence + barrier: Ct writes can't overlap final reads
  ushort* Ct = (ushort*)SM;
#pragma unroll
  for (int i = 0; i < FR; ++i) {
#pragma unroll
    for (int q4 = 0; q4 < 4; ++q4) {
      const int row = wr + i * 16 + (lane >> 4) * 4 + q4;
#pragma unroll
      for (int j = 0; j < FC; ++j) {
        const int col = wc + j * 16 + r15;
        float v = acc[i][j][q4];
        if (ADAPT) v = tanhf(v + biast[n0 + col]);
        Ct[row * BN + col] = f2b(v);
      }
    }
  }
  __syncthreads();
  constexpr int C8 = BN / 8;
  constexpr int UNITS = BM * C8;
#pragma unroll
  for (int u0 = 0; u0 < UNITS; u0 += 256) {
    const int u = u0 + tid;
    const int row = u / C8, c8 = u % C8;
    const int rl = m0 + row;
    if (rl < mcnt) {
      const int grow = ADAPT ? permt[rl] : rl;
      *(short8*)(Cout + (size_t)grow * ldC + n0 + c8 * 8) =
          *(const short8*)(Ct + row * BN + c8 * 8);
    }
  }
}

// ---------------- CSR gather-combine ----------------
template <bool LAST>
__global__ void k_combine(const ushort* __restrict__ Hall, const int* __restrict__ rowptr,
                          const int* __restrict__ epack, const float* __restrict__ invd,
                          const float* __restrict__ bias, void* __restrict__ outp, int N) {
  int v = blockIdx.x * 4 + (threadIdx.x >> 6);
  if (v >= N) return;
  int lane = threadIdx.x & 63;
  int e0 = rowptr[v], e1 = rowptr[v + 1];
  const uint2 s = *(const uint2*)(Hall + (size_t)v * LDH + NREL * D + lane * 4);
  float iv = invd[v];
  const float4 b4 = *(const float4*)(bias + lane * 4);

  float a0 = 0.f, a1 = 0.f, a2 = 0.f, a3 = 0.f;
  int e = e0;
  for (; e + 8 <= e1; e += 8) {
    uint2 u[8];
#pragma unroll
    for (int k = 0; k < 8; ++k) {
      int p = epack[e + k];
      u[k] = *(const uint2*)(Hall + (size_t)(p >> 3) * LDH + (p & 7) * D + lane * 4);
    }
#pragma unroll
    for (int k = 0; k < 8; ++k) {
      a0 += b2f(u[k].x & 0xffffu);
      a1 += __uint_as_float(u[k].x & 0xffff0000u);
      a2 += b2f(u[k].y & 0xffffu);
      a3 += __uint_as_float(u[k].y & 0xffff0000u);
    }
  }
  if (e + 4 <= e1) {
    uint2 u[4];
#pragma unroll
    for (int k = 0; k < 4; ++k) {
      int p = epack[e + k];
      u[k] = *(const uint2*)(Hall + (size_t)(p >> 3) * LDH + (p & 7) * D + lane * 4);
    }
#pragma unroll
    for (int k = 0; k < 4; ++k) {
      a0 += b2f(u[k].x & 0xffffu);
      a1 += __uint_as_float(u[k].x & 0xffff0000u);
      a2 += b2f(u[k].y & 0xffffu);
      a3 += __uint_as_float(u[k].y & 0xffff0000u);
    }
    e += 4;
  }
  for (; e < e1; ++e) {
    int p = epack[e];
    const uint2 u = *(const uint2*)(Hall + (size_t)(p >> 3) * LDH + (p & 7) * D + lane * 4);
    a0 += b2f(u.x & 0xffffu);
    a1 += __uint_as_float(u.x & 0xffff0000u);
    a2 += b2f(u.y & 0xffffu);
    a3 += __uint_as_float(u.y & 0xffff0000u);
  }
  float o0 = fmaxf(fmaf(a0, iv, b2f(s.x & 0xffffu)) + b4.x, 0.f);
  float o1 = fmaxf(fmaf(a1, iv, __uint_as_float(s.x & 0xffff0000u)) + b4.y, 0.f);
  float o2 = fmaxf(fmaf(a2, iv, b2f(s.y & 0xffffu)) + b4.z, 0.f);
  float o3 = fmaxf(fmaf(a3, iv, __uint_as_float(s.y & 0xffff0000u)) + b4.w, 0.f);
  if (LAST) {
    float4 o; o.x = o0; o.y = o1; o.z = o2; o.w = o3;
    ((float4*)outp)[(size_t)v * 64 + lane] = o;
  } else {
    ushort4 o; o.x = f2b(o0); o.y = f2b(o1); o.z = f2b(o2); o.w = f2b(o3);
    ((ushort4*)outp)[(size_t)v * 64 + lane] = o;
  }
}

extern "C" void kernel_launch(void* const* d_in, const int* in_sizes, int n_in,
                              void* d_out, int out_size, void* d_ws, size_t ws_size,
                              hipStream_t stream) {
  const float* X       = (const float*)d_in[0];
  const int*   ntype   = (const int*)d_in[1];
  const int*   eidx    = (const int*)d_in[2];
  const int*   etype   = (const int*)d_in[3];
  const float* adapt_W = (const float*)d_in[5];
  const float* adapt_b = (const float*)d_in[6];
  const float* W_rel   = (const float*)d_in[7];
  const float* W_self  = (const float*)d_in[8];
  const float* b_self  = (const float*)d_in[9];

  const int N = in_sizes[1];
  const int E = in_sizes[3];
  const int* src = eidx;
  const int* dst = eidx + E;

  char* ws = (char*)d_ws;
  size_t o = 0;
  auto alloc = [&](size_t bytes) { void* p = ws + o; o += (bytes + 255) & ~255ull; return p; };

  ushort* Hall  = (ushort*)alloc((size_t)N * LDH * 2);  // 71.7 MB; also aliases Xb
  ushort* Xb    = Hall;                                  // Xb dead before Hall written
  ushort* h     = (ushort*)alloc((size_t)N * D * 2);
  ushort* Wab   = (ushort*)alloc((size_t)NTYPES * D * DIN * 2);
  ushort* Wcat  = (ushort*)alloc((size_t)2 * NSLOT * D * D * 2);
  int*   deg    = (int*)alloc((size_t)N * 4);
  float* inv    = (float*)alloc((size_t)N * 4);
  int*   perm   = (int*)alloc((size_t)N * 4);
  int*   rowptr = (int*)alloc((size_t)(N + 1) * 4);
  int*   cursor = (int*)alloc((size_t)N * 4);
  int*   epack  = (int*)alloc((size_t)E * 4);
  int*   bsum   = (int*)alloc(1024 * 4);
  int*   blockcnt = (int*)alloc((size_t)1024 * NTYPES * 4);
  int*   boffset  = (int*)alloc((size_t)1024 * NTYPES * 4);
  int*   cnt    = (int*)alloc(NTYPES * 4);
  int*   offt   = (int*)alloc(NTYPES * 4);

  const int thr = 256;
  const int nbN = (N + thr - 1) / thr;            // 256-chunks of nodes
  const int nbE = (E + thr - 1) / thr;            // 256-chunks of edges
  const int nbN512 = (N + 511) / 512;             // 512-chunks for degree scan

  // L0: zero deg
  k_zero<<<nbN, thr, 0, stream>>>(deg, N);

  // L1: mega prep — cvtX | cvtW | packWcat | type-hist | degree (one launch)
  const int n4x = N * DIN / 4;
  const int n4w = NTYPES * D * DIN / 4;
  const int nx = (n4x + thr - 1) / thr;
  const int nw = (n4w + thr - 1) / thr;
  const int np = 2 * NSLOT * (D * D / 256);
  k_prep_mega<<<nx + nw + np + nbN + nbE, thr, 0, stream>>>(
      X, Xb, adapt_W, Wab, W_rel, W_self, Wcat, ntype, blockcnt, dst, deg,
      N, E, nx, nw, np, nbN, n4x, n4w);

  // L2: fused scans — type_scan (block 0) | 512-wide degree chunk scans
  k_scan2<<<1 + nbN512, 512, 0, stream>>>(blockcnt, boffset, cnt, offt, nbN,
                                          deg, rowptr, bsum, N);

  // L3: fused — type scatter (perm) | bsum exclusive scan (last block)
  k_scatter_bsum<<<nbN + 1, thr, 0, stream>>>(ntype, boffset, perm, N, nbN, bsum, nbN512);

  // L4: finalize rowptr/cursor/inv
  k_scan_add<<<nbN, thr, 0, stream>>>(rowptr, cursor, bsum, deg, inv, N, E);

  // L5: adaptation GEMM | edge counting-sort (fused — sort atomics hide under MFMA)
  const int mtA = (N + 63) / 64;
  const int nwgA = NTYPES * mtA * (D / 64);
  k_mfma_gemm<64, 64, D / 64, DIN, true, true, 6><<<nwgA + nbE, 256, 0, stream>>>(
      Xb, Wab, adapt_b, perm, cnt, offt, h, N, D, nwgA,
      src, dst, etype, cursor, epack, E);

  // L6-L9: two relational layers — 128x128 GEMM + CSR combine
  const int mtL = (N + 127) / 128;
  const int nwgL = mtL * (LDH / 128);
  for (int l = 0; l < 2; ++l) {
    const ushort* Wl = Wcat + (size_t)l * NSLOT * D * D;
    k_mfma_gemm<128, 128, LDH / 128, D, false, false, 4><<<nwgL, 256, 0, stream>>>(
        h, Wl, nullptr, nullptr, nullptr, nullptr, Hall, N, LDH, nwgL,
        nullptr, nullptr, nullptr, nullptr, nullptr, 0);
    if (l == 0)
      k_combine<false><<<(N + 3) / 4, 256, 0, stream>>>(Hall, rowptr, epack, inv,
                                                        b_self + (size_t)l * D, h, N);
    else
      k_combine<true><<<(N + 3) / 4, 256, 0, stream>>>(Hall, rowptr, epack, inv,
                                                       b_self + (size_t)l * D, d_out, N);
  }
}